// Round 4
// baseline (259.651 us; speedup 1.0000x reference)
//
#include <hip/hip_runtime.h>
#include <hip/hip_bf16.h>

// Problem constants (match reference)
#define NB 128          // graphs
#define NN 512          // nodes per graph
#define NF 128          // input/hidden feature dim
#define BN (NB*NN)      // 65536 total nodes
#define NE (BN*16)      // 1048576 edges
#define EPG 8192        // edges per graph (N*DEG_AVG)
#define WPR 16          // bitmap words per row (512 bits / 32)
#define ELLW 64         // ELL width (max padded degree)
#define QST 24          // poly w row stride in ushorts (48 B, 16-B aligned)
#define SST 72          // build-kernel ELL staging stride
#define WTS 136         // gemm Wt LDS stride in ushorts (272 B, 16-B aligned)

typedef short sh8 __attribute__((ext_vector_type(8)));
typedef float f32x4 __attribute__((ext_vector_type(4)));

static __device__ __forceinline__ unsigned short f2bf(float f) {
    unsigned u = __float_as_uint(f);
    u += 0x7fffu + ((u >> 16) & 1u);        // round-to-nearest-even
    return (unsigned short)(u >> 16);
}

// acc += bf16_low(pk)  /  acc += bf16_high(pk) via VOP3P dot2:
// D = S0.x*S1.x + S0.y*S1.y + S2 ; products exact (x1.0), +0 exact ->
// bitwise identical to shift+add, at half the instruction count.
#define DOT2LO(acc_, pk_, one_) \
    asm("v_dot2_f32_bf16 %0, %1, %2, %0" : "+v"(acc_) : "v"(pk_), "v"(one_))

// ---------------------------------------------------------------------------
// Fused adjacency + ELL build, one block per graph. LDS bitmap dedup.
// Rows ranked by degree; everything downstream lives in rank space.
// (unchanged)
// ---------------------------------------------------------------------------
__global__ __launch_bounds__(512) void build_ell_fused_kernel(
    const int* __restrict__ src, const int* __restrict__ dst,
    unsigned short* __restrict__ ell, int* __restrict__ ocnt,
    float* __restrict__ dinvr, int* __restrict__ perm)
{
    __shared__ unsigned bm[NN * WPR];   // 32 KB; later reused as ELL staging
    __shared__ int cs[NN];              // degree by row
    __shared__ int rdeg[NN];            // degree by rank
    __shared__ int irank[NN];           // row -> rank
    int g = blockIdx.x;
    int t = threadIdx.x;                // 0..511

    for (int i = t; i < NN * WPR; i += 512) bm[i] = 0u;
    __syncthreads();

    const int4* sg4 = (const int4*)(src + (size_t)g * EPG);
    const int4* dg4 = (const int4*)(dst + (size_t)g * EPG);
    for (int i = t; i < EPG / 4; i += 512) {
        int4 s4 = sg4[i];
        int4 d4 = dg4[i];
        int s, d;
        s = s4.x & (NN - 1); d = d4.x & (NN - 1);
        atomicOr(&bm[s * WPR + (d >> 5)], 1u << (d & 31));
        s = s4.y & (NN - 1); d = d4.y & (NN - 1);
        atomicOr(&bm[s * WPR + (d >> 5)], 1u << (d & 31));
        s = s4.z & (NN - 1); d = d4.z & (NN - 1);
        atomicOr(&bm[s * WPR + (d >> 5)], 1u << (d & 31));
        s = s4.w & (NN - 1); d = d4.w & (NN - 1);
        atomicOr(&bm[s * WPR + (d >> 5)], 1u << (d & 31));
    }
    __syncthreads();

    // extract this thread's row (row == t) into registers
    unsigned rw[WPR];
    #pragma unroll
    for (int w = 0; w < WPR; ++w) rw[w] = bm[t * WPR + w];
    int deg = 0;
    #pragma unroll
    for (int w = 0; w < WPR; ++w) deg += __popc(rw[w]);
    if (deg > ELLW) deg = ELLW;         // defensive
    cs[t] = deg;
    __syncthreads();                    // all bm reads done; cs visible

    // deterministic rank: ascending by (deg, row). LDS reads are broadcasts.
    int rk = 0;
    for (int i = 0; i < NN; ++i) {
        int di_ = cs[i];
        rk += (di_ < deg) || (di_ == deg && i < t);
    }
    rdeg[rk] = deg;
    irank[t] = rk;
    perm[(size_t)g * NN + rk] = t;
    dinvr[(size_t)g * NN + rk] = (deg > 0) ? rsqrtf((float)deg) : 0.0f;
    __syncthreads();

    if (t < NN / 8) {
        // ascending sort: oct max = last element of the oct
        int m = rdeg[t * 8 + 7];
        ocnt[(size_t)g * (NN / 8) + t] = (m + 3) & ~3;
    }

    // ELL staging (rank order, RANK-mapped entries) + coalesced writeout
    unsigned short* els = (unsigned short*)bm;
    for (int qtr = 0; qtr < 4; ++qtr) {
        if ((rk >> 7) == qtr) {
            unsigned short* er = &els[(rk & 127) * SST];
            int c = 0;
            #pragma unroll
            for (int w = 0; w < WPR; ++w) {
                unsigned bits = rw[w];
                while (bits) {
                    int j = __ffs(bits) - 1;
                    bits &= bits - 1;
                    if (c < ELLW) er[c] = (unsigned short)irank[w * 32 + j];
                    ++c;
                }
            }
            if (c > ELLW) c = ELLW;
            for (int p = c; p < ELLW; ++p) er[p] = (unsigned short)NN;
        }
        __syncthreads();
        unsigned short* outb = ell + ((size_t)g * NN + qtr * 128) * ELLW;
        for (int idx = t; idx < 1024; idx += 512) {
            int r2 = idx >> 3, sg2 = idx & 7;
            uint4 v = *(const uint4*)&els[r2 * SST + sg2 * 8];
            *(uint4*)&outb[(size_t)r2 * ELLW + sg2 * 8] = v;
        }
        __syncthreads();
    }
}

// ---------------------------------------------------------------------------
// Fused 3-hop poly conv in RANK space, one block per (graph, feature-EIGHTH).
// grid = 1024 blocks of 512 thr, 26.7 KB LDS.
// R4: INTERLEAVED DUAL-GROUP GATHER. R3's aggregate counters put the LDS
// pipe at ~64% busy (30us of 47) with VALU 41% overlapped — the gap is
// unhidden ds_read latency (only 4 independent b128s in flight per thread).
// Both group bounds are wave-uniform and co[1] >= co[0] (ascending ranks,
// group B is the high-degree mirror), so the two gather loops fuse into one
// loop over co[1] with a uniform p<co[0] guard: 8 independent ds_read_b128
// + 64 dot2 per iteration while both groups are live. Antithetic pairing
// (R3) and geometry (R2) retained. launch_bounds(512,4): min-waves=8 caused
// a 32-VGPR spill squeeze (R1). g = bid & 127: same-graph blocks -> one XCD.
// ---------------------------------------------------------------------------
__global__ __launch_bounds__(512, 4) void poly_fused_kernel(
    const float* __restrict__ xin,            // [BN, NF]
    float* __restrict__ accout,               // [BN, NF] rank space
    const unsigned short* __restrict__ ell,   // [BN][ELLW] rank entries
    const int* __restrict__ ocnt,             // [BN/8] padded oct counts
    const float* __restrict__ dinvr,          // [BN] rank-indexed
    const int* __restrict__ perm,             // [BN] rank -> row
    int permuteIn)
{
    extern __shared__ float lds[];
    unsigned short* w = (unsigned short*)lds;        // (NN+1) rows * QST
    float* dsh = lds + ((NN + 1) * QST * 2) / 4;     // NN floats

    int b = blockIdx.x;
    int g = b & 127;                     // graph (same-graph blocks -> same XCD)
    int q = b >> 7;                      // feature eighth (16 feats)
    int t = threadIdx.x;                 // 0..511
    int lane = t & 63;
    int wid  = t >> 6;                   // 0..7
    int slot = lane >> 1;                // 0..31
    int fb   = lane & 1;                 // 0..1 (8 feats each)

    unsigned one_lo = 0x00003F80u;       // bf16x2 (1.0, 0.0)
    unsigned one_hi = 0x3F800000u;       // bf16x2 (0.0, 1.0)

    if (t < NN) dsh[t] = dinvr[(size_t)g * NN + t];
    if (t < QST) w[NN * QST + t] = 0;    // zero sentinel row (bf16 0)

    // antithetic group bases: A = low-degree window, B = mirrored high-degree
    int rb[2];
    rb[0] = wid * 32;                    // groups 0..7   (ranks 0..255)
    rb[1] = (15 - wid) * 32;             // groups 15..8  (ranks 256..511)

    // input row for each group: perm'd for layer 1, identity (coalesced) else
    int px[2];
    if (permuteIn) {
        const int* pmg = perm + (size_t)g * NN;
        px[0] = pmg[rb[0] + slot];
        px[1] = pmg[rb[1] + slot];
    } else {
        px[0] = rb[0] + slot;
        px[1] = rb[1] + slot;
    }

    const float* xg = xin + (size_t)g * NN * NF + q * 16 + fb * 8;

    float acc[2][8];
    #pragma unroll
    for (int x = 0; x < 2; ++x) {
        int row = px[x];
        float4 a0 = *(const float4*)&xg[(size_t)row * NF];
        float4 a1 = *(const float4*)&xg[(size_t)row * NF + 4];
        acc[x][0] = a0.x; acc[x][1] = a0.y; acc[x][2] = a0.z; acc[x][3] = a0.w;
        acc[x][4] = a1.x; acc[x][5] = a1.y; acc[x][6] = a1.z; acc[x][7] = a1.w;
    }

    // per-group counts: max of the group's four oct counts (wave-uniform;
    // within a 32-rank window of the ascending sort the spread is small)
    const int* oc = ocnt + (size_t)g * (NN / 8);
    int co[2];
    #pragma unroll
    for (int x = 0; x < 2; ++x) {
        int o0 = (rb[x] >> 3);
        int m0 = max(oc[o0], oc[o0 + 1]);
        int m1 = max(oc[o0 + 2], oc[o0 + 3]);
        co[x] = __builtin_amdgcn_readfirstlane(max(m0, m1));
    }

    __syncthreads();                     // dsh + sentinel ready

    #pragma unroll
    for (int x = 0; x < 2; ++x) {
        int rr = rb[x] + slot;           // rank position
        float di = dsh[rr];
        unsigned pk[4];
        #pragma unroll
        for (int k = 0; k < 4; ++k) {
            unsigned lo = (unsigned)f2bf(di * acc[x][2 * k]);
            unsigned hi = (unsigned)f2bf(di * acc[x][2 * k + 1]);
            pk[k] = lo | (hi << 16);
        }
        *(uint4*)&w[rr * QST + fb * 8] = make_uint4(pk[0], pk[1], pk[2], pk[3]);
    }
    __syncthreads();                     // w init ready

    const unsigned short* elb0 =
        ell + ((size_t)g * NN + rb[0] + slot) * ELLW;
    const unsigned short* elb1 =
        ell + ((size_t)g * NN + rb[1] + slot) * ELLW;

    int c0 = co[0];
    int c1 = co[1];                      // c1 >= c0 (B is high-degree mirror)

    for (int hop = 0; hop < 3; ++hop) {
        float sA[8], sB[8];
        #pragma unroll
        for (int k = 0; k < 8; ++k) { sA[k] = 0.0f; sB[k] = 0.0f; }

        ushort4 curA = *(const ushort4*)elb0;
        ushort4 curB = *(const ushort4*)elb1;

        for (int p = 0; p < c1; p += 4) {
            // prefetch next index batches (in flight across the body)
            ushort4 nxtA = curA, nxtB = curB;
            if (p + 4 < c0) nxtA = *(const ushort4*)(elb0 + p + 4);
            if (p + 4 < c1) nxtB = *(const ushort4*)(elb1 + p + 4);

            if (p < c0) {                // wave-uniform guard (group A live)
                uint4 a0 = *(const uint4*)&w[(int)curA.x * QST + fb * 8];
                uint4 a1 = *(const uint4*)&w[(int)curA.y * QST + fb * 8];
                uint4 a2 = *(const uint4*)&w[(int)curA.z * QST + fb * 8];
                uint4 a3 = *(const uint4*)&w[(int)curA.w * QST + fb * 8];
                uint4 b0 = *(const uint4*)&w[(int)curB.x * QST + fb * 8];
                uint4 b1 = *(const uint4*)&w[(int)curB.y * QST + fb * 8];
                uint4 b2 = *(const uint4*)&w[(int)curB.z * QST + fb * 8];
                uint4 b3 = *(const uint4*)&w[(int)curB.w * QST + fb * 8];
                unsigned da[4][4] = {{a0.x, a0.y, a0.z, a0.w},
                                     {a1.x, a1.y, a1.z, a1.w},
                                     {a2.x, a2.y, a2.z, a2.w},
                                     {a3.x, a3.y, a3.z, a3.w}};
                unsigned db[4][4] = {{b0.x, b0.y, b0.z, b0.w},
                                     {b1.x, b1.y, b1.z, b1.w},
                                     {b2.x, b2.y, b2.z, b2.w},
                                     {b3.x, b3.y, b3.z, b3.w}};
                #pragma unroll
                for (int n = 0; n < 4; ++n) {
                    #pragma unroll
                    for (int k = 0; k < 4; ++k) {
                        DOT2LO(sA[2 * k],     da[n][k], one_lo);
                        DOT2LO(sA[2 * k + 1], da[n][k], one_hi);
                        DOT2LO(sB[2 * k],     db[n][k], one_lo);
                        DOT2LO(sB[2 * k + 1], db[n][k], one_hi);
                    }
                }
            } else {                     // only group B remains
                uint4 b0 = *(const uint4*)&w[(int)curB.x * QST + fb * 8];
                uint4 b1 = *(const uint4*)&w[(int)curB.y * QST + fb * 8];
                uint4 b2 = *(const uint4*)&w[(int)curB.z * QST + fb * 8];
                uint4 b3 = *(const uint4*)&w[(int)curB.w * QST + fb * 8];
                unsigned db[4][4] = {{b0.x, b0.y, b0.z, b0.w},
                                     {b1.x, b1.y, b1.z, b1.w},
                                     {b2.x, b2.y, b2.z, b2.w},
                                     {b3.x, b3.y, b3.z, b3.w}};
                #pragma unroll
                for (int n = 0; n < 4; ++n) {
                    #pragma unroll
                    for (int k = 0; k < 4; ++k) {
                        DOT2LO(sB[2 * k],     db[n][k], one_lo);
                        DOT2LO(sB[2 * k + 1], db[n][k], one_hi);
                    }
                }
            }
            curA = nxtA;
            curB = nxtB;
        }

        __syncthreads();                 // all reads of old w done
        #pragma unroll
        for (int x = 0; x < 2; ++x) {
            float* sx = x ? sB : sA;
            int rr = rb[x] + slot;
            float di = dsh[rr];
            unsigned pk[4];
            #pragma unroll
            for (int k = 0; k < 4; ++k) {
                float zlo = di * sx[2 * k];
                float zhi = di * sx[2 * k + 1];
                acc[x][2 * k]     += zlo;
                acc[x][2 * k + 1] += zhi;
                unsigned lo = (unsigned)f2bf(di * zlo);
                unsigned hi = (unsigned)f2bf(di * zhi);
                pk[k] = lo | (hi << 16);
            }
            *(uint4*)&w[rr * QST + fb * 8] = make_uint4(pk[0], pk[1], pk[2], pk[3]);
        }
        __syncthreads();                 // new w visible
    }

    // coalesced write at rank positions
    float* og = accout + (size_t)g * NN * NF + q * 16 + fb * 8;
    #pragma unroll
    for (int x = 0; x < 2; ++x) {
        int rr = rb[x] + slot;
        *(float4*)&og[(size_t)rr * NF] =
            make_float4(acc[x][0], acc[x][1], acc[x][2], acc[x][3]);
        *(float4*)&og[(size_t)rr * NF + 4] =
            make_float4(acc[x][4], acc[x][5], acc[x][6], acc[x][7]);
    }
}

// ---------------------------------------------------------------------------
// MFMA bf16 GEMM: Y[65536,128] = relu(bf16(X) @ bf16(W) + b), optional fused
// deterministic mean-pool partials. (unchanged)
// ---------------------------------------------------------------------------
__global__ __launch_bounds__(256, 2) void gemm_bias_relu_kernel(
    const float* __restrict__ X, const float* __restrict__ W,
    const float* __restrict__ b, float* __restrict__ Y,
    float* __restrict__ partial, int fuse)
{
    __shared__ __align__(16) unsigned short Wt[NF * WTS];  // [n][k] bf16
    __shared__ float part[4 * NF];

    int t = threadIdx.x;

    // stage Wt = W^T in bf16
    for (int i = t; i < NF * NF / 4; i += 256) {
        int k = i >> 5;                 // W row
        int n4 = (i & 31) * 4;          // W col group
        float4 wv = ((const float4*)W)[i];
        Wt[(n4 + 0) * WTS + k] = f2bf(wv.x);
        Wt[(n4 + 1) * WTS + k] = f2bf(wv.y);
        Wt[(n4 + 2) * WTS + k] = f2bf(wv.z);
        Wt[(n4 + 3) * WTS + k] = f2bf(wv.w);
    }
    __syncthreads();

    int lane = t & 63;
    int wid  = t >> 6;                  // 0..3
    int quad = lane >> 4;               // 0..3
    int l16  = lane & 15;
    int rowA0 = blockIdx.x * 128 + wid * 32;

    // A fragments: af[m][kk], m in {0,1} (row halves), kk = K-step
    union { unsigned short u[8]; sh8 v; } af[2][4];
    #pragma unroll
    for (int m = 0; m < 2; ++m) {
        int r = rowA0 + m * 16 + l16;
        const float* xr = X + (size_t)r * NF + quad * 8;
        #pragma unroll
        for (int kk = 0; kk < 4; ++kk) {
            float4 x0 = *(const float4*)(xr + kk * 32);
            float4 x1 = *(const float4*)(xr + kk * 32 + 4);
            af[m][kk].u[0] = f2bf(x0.x); af[m][kk].u[1] = f2bf(x0.y);
            af[m][kk].u[2] = f2bf(x0.z); af[m][kk].u[3] = f2bf(x0.w);
            af[m][kk].u[4] = f2bf(x1.x); af[m][kk].u[5] = f2bf(x1.y);
            af[m][kk].u[6] = f2bf(x1.z); af[m][kk].u[7] = f2bf(x1.w);
        }
    }

    f32x4 acc[2][8];
    #pragma unroll
    for (int m = 0; m < 2; ++m)
        #pragma unroll
        for (int c = 0; c < 8; ++c) acc[m][c] = (f32x4){0.f, 0.f, 0.f, 0.f};

    #pragma unroll
    for (int c = 0; c < 8; ++c) {
        const unsigned short* wb = &Wt[(c * 16 + l16) * WTS + quad * 8];
        #pragma unroll
        for (int kk = 0; kk < 4; ++kk) {
            union { uint4 q; sh8 v; } bf_;
            bf_.q = *(const uint4*)(wb + kk * 32);
            acc[0][c] = __builtin_amdgcn_mfma_f32_16x16x32_bf16(
                af[0][kk].v, bf_.v, acc[0][c], 0, 0, 0);
            acc[1][c] = __builtin_amdgcn_mfma_f32_16x16x32_bf16(
                af[1][kk].v, bf_.v, acc[1][c], 0, 0, 0);
        }
    }

    float psum[8];
    #pragma unroll
    for (int c = 0; c < 8; ++c) psum[c] = 0.0f;

    #pragma unroll
    for (int c = 0; c < 8; ++c) {
        int col = c * 16 + l16;
        float bias = b[col];
        #pragma unroll
        for (int m = 0; m < 2; ++m) {
            #pragma unroll
            for (int reg = 0; reg < 4; ++reg) {
                int r = rowA0 + m * 16 + quad * 4 + reg;
                float v = fmaxf(acc[m][c][reg] + bias, 0.0f);
                Y[(size_t)r * NF + col] = v;
                psum[c] += v;
            }
        }
    }

    if (fuse) {
        // deterministic cross-quad reduction, then cross-wave LDS tree
        #pragma unroll
        for (int c = 0; c < 8; ++c) {
            float v = psum[c];
            v += __shfl_xor(v, 16);
            v += __shfl_xor(v, 32);
            if (lane < 16) part[wid * NF + c * 16 + lane] = v;
        }
        __syncthreads();
        if (t < NF) {
            float s = part[t] + part[NF + t] + part[2 * NF + t]
                    + part[3 * NF + t];
            partial[(size_t)blockIdx.x * NF + t] = s;
        }
    }
}

// ---------------------------------------------------------------------------
// Readout: per graph, mean-pool from gemm2 partials (4 blocks/graph) + MLP.
// ---------------------------------------------------------------------------
__global__ __launch_bounds__(128) void readout_kernel(
    const float* __restrict__ partial,   // [BN/128][NF]
    const float* __restrict__ Wr1, const float* __restrict__ br1,
    const float* __restrict__ Wr2, const float* __restrict__ br2,
    float* __restrict__ out)
{
    __shared__ float hsh[NF];
    __shared__ float r1[64];

    int g = blockIdx.x;
    int t = threadIdx.x;

    const float* pg = partial + (size_t)g * 4 * NF;
    float s = 0.0f;
    #pragma unroll
    for (int j = 0; j < 4; ++j) s += pg[j * NF + t];
    hsh[t] = s * (1.0f / (float)NN);
    __syncthreads();

    if (t < 64) {
        float a = br1[t];
        #pragma unroll 8
        for (int k = 0; k < NF; ++k) a += hsh[k] * Wr1[k * 64 + t];
        r1[t] = fmaxf(a, 0.0f);
    }
    __syncthreads();

    if (t < 64) {
        float v = r1[t] * Wr2[t];
        #pragma unroll
        for (int off = 32; off; off >>= 1) v += __shfl_down(v, off);
        if (t == 0) out[g] = v + br2[0];
    }
}

// ---------------------------------------------------------------------------
extern "C" void kernel_launch(void* const* d_in, const int* in_sizes, int n_in,
                              void* d_out, int out_size, void* d_ws, size_t ws_size,
                              hipStream_t stream)
{
    const float* X    = (const float*)d_in[0];
    // d_in[1] = batch (unused; nodes already grouped per graph)
    const int*   ei   = (const int*)d_in[2];
    const float* W1   = (const float*)d_in[3];
    const float* b1   = (const float*)d_in[4];
    const float* W2   = (const float*)d_in[5];
    const float* b2   = (const float*)d_in[6];
    const float* Wr1  = (const float*)d_in[7];
    const float* br1  = (const float*)d_in[8];
    const float* Wr2  = (const float*)d_in[9];
    const float* br2  = (const float*)d_in[10];
    float* out = (float*)d_out;

    const int* src = ei;
    const int* dst = ei + NE;

    // workspace layout
    char* ws = (char*)d_ws;
    float*          dinvr   = (float*)(ws);                          // 256 KB
    int*            ocnt    = (int*)(ws + (size_t)256 * 1024);       // 32 KB
    int*            perm    = (int*)(ws + (size_t)512 * 1024);       // 256 KB
    float*          partial = (float*)(ws + (size_t)768 * 1024);     // 256 KB
    unsigned short* ell     = (unsigned short*)(ws + (size_t)1024 * 1024); // 8 MB
    float*          buf0    = (float*)(ws + (size_t)16384 * 1024);   // 32 MB
    float*          buf1    = (float*)(ws + (size_t)49152 * 1024);   // 32 MB

    // fused adjacency+ELL build; rank-space outputs
    build_ell_fused_kernel<<<NB, 512, 0, stream>>>(src, dst, ell, ocnt, dinvr,
                                                   perm);

    // bf16 w rows (513 * 48 B) + dsh (512 floats) = 26,672 B
    const size_t LDSSZ = (size_t)(NN + 1) * QST * 2 + NN * 4;

    // ---- Layer 1 (X gathered via perm into rank space)
    poly_fused_kernel<<<NB * 8, 512, LDSSZ, stream>>>(X, buf0, ell, ocnt,
                                                      dinvr, perm, 1);
    gemm_bias_relu_kernel<<<BN / 128, 256, 0, stream>>>(buf0, W1, b1, buf1,
                                                        partial, 0);

    // ---- Layer 2 (all rank space, fully coalesced)
    poly_fused_kernel<<<NB * 8, 512, LDSSZ, stream>>>(buf1, buf0, ell, ocnt,
                                                      dinvr, perm, 0);
    gemm_bias_relu_kernel<<<BN / 128, 256, 0, stream>>>(buf0, W2, b2, buf1,
                                                        partial, 1);

    // ---- Readout from partials
    readout_kernel<<<NB, 128, 0, stream>>>(partial, Wr1, br1, Wr2, br2, out);
}

// Round 5
// 246.273 us; speedup vs baseline: 1.0543x; 1.0543x over previous
//
#include <hip/hip_runtime.h>
#include <hip/hip_bf16.h>

// Problem constants (match reference)
#define NB 128          // graphs
#define NN 512          // nodes per graph
#define NF 128          // input/hidden feature dim
#define BN (NB*NN)      // 65536 total nodes
#define NE (BN*16)      // 1048576 edges
#define EPG 8192        // edges per graph (N*DEG_AVG)
#define WPR 16          // bitmap words per row (512 bits / 32)
#define ELLW 64         // ELL width (max padded degree)
#define QST 32          // poly w row stride in ushorts (64 B: stride==bank-run)
#define SST 72          // build-kernel ELL staging stride
#define WTS 136         // gemm Wt LDS stride in ushorts (272 B, 16-B aligned)

typedef short sh8 __attribute__((ext_vector_type(8)));
typedef float f32x4 __attribute__((ext_vector_type(4)));

static __device__ __forceinline__ unsigned short f2bf(float f) {
    unsigned u = __float_as_uint(f);
    u += 0x7fffu + ((u >> 16) & 1u);        // round-to-nearest-even
    return (unsigned short)(u >> 16);
}

// acc += bf16_low(pk)  /  acc += bf16_high(pk) via VOP3P dot2:
// D = S0.x*S1.x + S0.y*S1.y + S2 ; products exact (x1.0), +0 exact ->
// bitwise identical to shift+add, at half the instruction count.
#define DOT2LO(acc_, pk_, one_) \
    asm("v_dot2_f32_bf16 %0, %1, %2, %0" : "+v"(acc_) : "v"(pk_), "v"(one_))

// ---------------------------------------------------------------------------
// Fused adjacency + ELL build, one block per graph. LDS bitmap dedup.
// Rows ranked by degree; everything downstream lives in rank space.
// (unchanged)
// ---------------------------------------------------------------------------
__global__ __launch_bounds__(512) void build_ell_fused_kernel(
    const int* __restrict__ src, const int* __restrict__ dst,
    unsigned short* __restrict__ ell, int* __restrict__ ocnt,
    float* __restrict__ dinvr, int* __restrict__ perm)
{
    __shared__ unsigned bm[NN * WPR];   // 32 KB; later reused as ELL staging
    __shared__ int cs[NN];              // degree by row
    __shared__ int rdeg[NN];            // degree by rank
    __shared__ int irank[NN];           // row -> rank
    int g = blockIdx.x;
    int t = threadIdx.x;                // 0..511

    for (int i = t; i < NN * WPR; i += 512) bm[i] = 0u;
    __syncthreads();

    const int4* sg4 = (const int4*)(src + (size_t)g * EPG);
    const int4* dg4 = (const int4*)(dst + (size_t)g * EPG);
    for (int i = t; i < EPG / 4; i += 512) {
        int4 s4 = sg4[i];
        int4 d4 = dg4[i];
        int s, d;
        s = s4.x & (NN - 1); d = d4.x & (NN - 1);
        atomicOr(&bm[s * WPR + (d >> 5)], 1u << (d & 31));
        s = s4.y & (NN - 1); d = d4.y & (NN - 1);
        atomicOr(&bm[s * WPR + (d >> 5)], 1u << (d & 31));
        s = s4.z & (NN - 1); d = d4.z & (NN - 1);
        atomicOr(&bm[s * WPR + (d >> 5)], 1u << (d & 31));
        s = s4.w & (NN - 1); d = d4.w & (NN - 1);
        atomicOr(&bm[s * WPR + (d >> 5)], 1u << (d & 31));
    }
    __syncthreads();

    // extract this thread's row (row == t) into registers
    unsigned rw[WPR];
    #pragma unroll
    for (int w = 0; w < WPR; ++w) rw[w] = bm[t * WPR + w];
    int deg = 0;
    #pragma unroll
    for (int w = 0; w < WPR; ++w) deg += __popc(rw[w]);
    if (deg > ELLW) deg = ELLW;         // defensive
    cs[t] = deg;
    __syncthreads();                    // all bm reads done; cs visible

    // deterministic rank: ascending by (deg, row). LDS reads are broadcasts.
    int rk = 0;
    for (int i = 0; i < NN; ++i) {
        int di_ = cs[i];
        rk += (di_ < deg) || (di_ == deg && i < t);
    }
    rdeg[rk] = deg;
    irank[t] = rk;
    perm[(size_t)g * NN + rk] = t;
    dinvr[(size_t)g * NN + rk] = (deg > 0) ? rsqrtf((float)deg) : 0.0f;
    __syncthreads();

    if (t < NN / 8) {
        // ascending sort: oct max = last element of the oct
        int m = rdeg[t * 8 + 7];
        ocnt[(size_t)g * (NN / 8) + t] = (m + 3) & ~3;
    }

    // ELL staging (rank order, RANK-mapped entries) + coalesced writeout
    unsigned short* els = (unsigned short*)bm;
    for (int qtr = 0; qtr < 4; ++qtr) {
        if ((rk >> 7) == qtr) {
            unsigned short* er = &els[(rk & 127) * SST];
            int c = 0;
            #pragma unroll
            for (int w = 0; w < WPR; ++w) {
                unsigned bits = rw[w];
                while (bits) {
                    int j = __ffs(bits) - 1;
                    bits &= bits - 1;
                    if (c < ELLW) er[c] = (unsigned short)irank[w * 32 + j];
                    ++c;
                }
            }
            if (c > ELLW) c = ELLW;
            for (int p = c; p < ELLW; ++p) er[p] = (unsigned short)NN;
        }
        __syncthreads();
        unsigned short* outb = ell + ((size_t)g * NN + qtr * 128) * ELLW;
        for (int idx = t; idx < 1024; idx += 512) {
            int r2 = idx >> 3, sg2 = idx & 7;
            uint4 v = *(const uint4*)&els[r2 * SST + sg2 * 8];
            *(uint4*)&outb[(size_t)r2 * ELLW + sg2 * 8] = v;
        }
        __syncthreads();
    }
}

// ---------------------------------------------------------------------------
// Fused 3-hop poly conv in RANK space, one block per (graph, feature-QUARTER).
// grid = 512 blocks of 512 thr, 34.9 KB LDS -> 2 blocks/CU.
// R5: BANK-UNIFORM COOPERATIVE GATHER. ds_read_b128 starts are 16-B aligned
// => start banks are multiples of 4; with 48-B rows the 32 random rows/wave
// hit 8 start classes with 8-dword runs (E[max bank load] ~11.5 vs ideal 8,
// factor ~1.44 — matches the 6.03M conflict count). Now 4 lanes read one
// 64-B row cooperatively: stride == 64 B => start classes {0,16} with
// 16-dword runs per row, E[max] ~9.6 (factor ~1.2); w-stores are exactly
// conflict-free (even/odd ranks alternate half-banks). Each thread owns
// 4 ranks via 4 statically-unrolled passes (runtime-indexed reg arrays go
// to scratch otherwise); wave == 2 octs per pass so counts are naturally
// wave-uniform; passes 2,3 flip wave order (antithetic, R3 lesson).
// bf16-pack BEFORE the barrier so staging is 16 uints, not 32 floats.
// launch_bounds(512,4): cap 128 VGPR (est ~120); min-waves=8 squeezed to
// spill in R1. g = bid & 127: same-graph blocks -> one XCD's L2 for ELL.
// ---------------------------------------------------------------------------
__global__ __launch_bounds__(512, 4) void poly_fused_kernel(
    const float* __restrict__ xin,            // [BN, NF]
    float* __restrict__ accout,               // [BN, NF] rank space
    const unsigned short* __restrict__ ell,   // [BN][ELLW] rank entries
    const int* __restrict__ ocnt,             // [BN/8] padded oct counts
    const float* __restrict__ dinvr,          // [BN] rank-indexed
    const int* __restrict__ perm,             // [BN] rank -> row
    int permuteIn)
{
    extern __shared__ float lds[];
    unsigned short* w = (unsigned short*)lds;        // (NN+1) rows * QST
    float* dsh = lds + ((NN + 1) * QST * 2) / 4;     // NN floats

    int b = blockIdx.x;
    int g = b & 127;                     // graph (same-graph blocks -> same XCD)
    int q = b >> 7;                      // feature quarter (32 feats)
    int t = threadIdx.x;                 // 0..511
    int wid = t >> 6;                    // 0..7
    int qd  = (t >> 2) & 15;             // quad-in-wave 0..15
    int fbq = t & 3;                     // 16-B chunk 0..3 (8 feats)

    unsigned one_lo = 0x00003F80u;       // bf16x2 (1.0, 0.0)
    unsigned one_hi = 0x3F800000u;       // bf16x2 (0.0, 1.0)

    if (t < NN) dsh[t] = dinvr[(size_t)g * NN + t];
    if (t < QST) w[NN * QST + t] = 0;    // zero sentinel row (bf16 0)

    // 4 passes of 128 ranks; wave handles 16 consecutive ranks (= 2 octs)
    // per pass. Passes 2,3 flip wave order for load balance.
    int rnk[4];
    #pragma unroll
    for (int x = 0; x < 4; ++x) {
        int wl = (x >= 2) ? (7 - wid) : wid;
        rnk[x] = x * 128 + wl * 16 + qd;
    }

    // wave-uniform padded counts: the wave's 16 ranks span octs ob, ob+1
    const int* oc = ocnt + (size_t)g * (NN / 8);
    int co[4];
    #pragma unroll
    for (int x = 0; x < 4; ++x) {
        int ob = (rnk[x] - qd) >> 3;
        co[x] = __builtin_amdgcn_readfirstlane(max(oc[ob], oc[ob + 1]));
    }

    // input row per pass: perm'd for layer 1, identity (coalesced) else
    int px[4];
    if (permuteIn) {
        const int* pmg = perm + (size_t)g * NN;
        #pragma unroll
        for (int x = 0; x < 4; ++x) px[x] = pmg[rnk[x]];
    } else {
        #pragma unroll
        for (int x = 0; x < 4; ++x) px[x] = rnk[x];
    }

    const float* xg = xin + (size_t)g * NN * NF + q * 32 + fbq * 8;

    float acc[4][8];
    #pragma unroll
    for (int x = 0; x < 4; ++x) {
        int row = px[x];
        float4 a0 = *(const float4*)&xg[(size_t)row * NF];
        float4 a1 = *(const float4*)&xg[(size_t)row * NF + 4];
        acc[x][0] = a0.x; acc[x][1] = a0.y; acc[x][2] = a0.z; acc[x][3] = a0.w;
        acc[x][4] = a1.x; acc[x][5] = a1.y; acc[x][6] = a1.z; acc[x][7] = a1.w;
    }

    __syncthreads();                     // dsh + sentinel ready

    #pragma unroll
    for (int x = 0; x < 4; ++x) {
        float di = dsh[rnk[x]];
        unsigned pk[4];
        #pragma unroll
        for (int k = 0; k < 4; ++k) {
            unsigned lo = (unsigned)f2bf(di * acc[x][2 * k]);
            unsigned hi = (unsigned)f2bf(di * acc[x][2 * k + 1]);
            pk[k] = lo | (hi << 16);
        }
        *(uint4*)&w[rnk[x] * QST + fbq * 8] = make_uint4(pk[0], pk[1], pk[2], pk[3]);
    }
    __syncthreads();                     // w init ready

    for (int hop = 0; hop < 3; ++hop) {
        unsigned pst[4][4];              // staged bf16x2 packs per pass
        #pragma unroll
        for (int x = 0; x < 4; ++x) {
            const unsigned short* el =
                ell + ((size_t)g * NN + rnk[x]) * ELLW;
            int cnt = co[x];
            float s[8];
            #pragma unroll
            for (int k = 0; k < 8; ++k) s[k] = 0.0f;

            ushort4 cur = *(const ushort4*)el;     // quad-uniform load
            for (int p = 0; p < cnt; p += 4) {
                ushort4 nxt = cur;
                if (p + 4 < cnt) nxt = *(const ushort4*)(el + p + 4);
                uint4 v0 = *(const uint4*)&w[(int)cur.x * QST + fbq * 8];
                uint4 v1 = *(const uint4*)&w[(int)cur.y * QST + fbq * 8];
                uint4 v2 = *(const uint4*)&w[(int)cur.z * QST + fbq * 8];
                uint4 v3 = *(const uint4*)&w[(int)cur.w * QST + fbq * 8];
                unsigned d[4][4] = {{v0.x, v0.y, v0.z, v0.w},
                                    {v1.x, v1.y, v1.z, v1.w},
                                    {v2.x, v2.y, v2.z, v2.w},
                                    {v3.x, v3.y, v3.z, v3.w}};
                #pragma unroll
                for (int n = 0; n < 4; ++n) {
                    #pragma unroll
                    for (int k = 0; k < 4; ++k) {
                        DOT2LO(s[2 * k],     d[n][k], one_lo);
                        DOT2LO(s[2 * k + 1], d[n][k], one_hi);
                    }
                }
                cur = nxt;
            }

            // fold into acc + pack NOW (dsh is stable): staging = 4 uints
            float di = dsh[rnk[x]];
            #pragma unroll
            for (int k = 0; k < 4; ++k) {
                float zlo = di * s[2 * k];
                float zhi = di * s[2 * k + 1];
                acc[x][2 * k]     += zlo;
                acc[x][2 * k + 1] += zhi;
                unsigned lo = (unsigned)f2bf(di * zlo);
                unsigned hi = (unsigned)f2bf(di * zhi);
                pst[x][k] = lo | (hi << 16);
            }
        }
        __syncthreads();                 // all reads of old w done
        #pragma unroll
        for (int x = 0; x < 4; ++x) {
            *(uint4*)&w[rnk[x] * QST + fbq * 8] =
                make_uint4(pst[x][0], pst[x][1], pst[x][2], pst[x][3]);
        }
        __syncthreads();                 // new w visible
    }

    // coalesced write at rank positions
    float* og = accout + (size_t)g * NN * NF + q * 32 + fbq * 8;
    #pragma unroll
    for (int x = 0; x < 4; ++x) {
        int rr = rnk[x];
        *(float4*)&og[(size_t)rr * NF] =
            make_float4(acc[x][0], acc[x][1], acc[x][2], acc[x][3]);
        *(float4*)&og[(size_t)rr * NF + 4] =
            make_float4(acc[x][4], acc[x][5], acc[x][6], acc[x][7]);
    }
}

// ---------------------------------------------------------------------------
// MFMA bf16 GEMM: Y[65536,128] = relu(bf16(X) @ bf16(W) + b), optional fused
// deterministic mean-pool partials. (unchanged)
// ---------------------------------------------------------------------------
__global__ __launch_bounds__(256, 2) void gemm_bias_relu_kernel(
    const float* __restrict__ X, const float* __restrict__ W,
    const float* __restrict__ b, float* __restrict__ Y,
    float* __restrict__ partial, int fuse)
{
    __shared__ __align__(16) unsigned short Wt[NF * WTS];  // [n][k] bf16
    __shared__ float part[4 * NF];

    int t = threadIdx.x;

    // stage Wt = W^T in bf16
    for (int i = t; i < NF * NF / 4; i += 256) {
        int k = i >> 5;                 // W row
        int n4 = (i & 31) * 4;          // W col group
        float4 wv = ((const float4*)W)[i];
        Wt[(n4 + 0) * WTS + k] = f2bf(wv.x);
        Wt[(n4 + 1) * WTS + k] = f2bf(wv.y);
        Wt[(n4 + 2) * WTS + k] = f2bf(wv.z);
        Wt[(n4 + 3) * WTS + k] = f2bf(wv.w);
    }
    __syncthreads();

    int lane = t & 63;
    int wid  = t >> 6;                  // 0..3
    int quad = lane >> 4;               // 0..3
    int l16  = lane & 15;
    int rowA0 = blockIdx.x * 128 + wid * 32;

    // A fragments: af[m][kk], m in {0,1} (row halves), kk = K-step
    union { unsigned short u[8]; sh8 v; } af[2][4];
    #pragma unroll
    for (int m = 0; m < 2; ++m) {
        int r = rowA0 + m * 16 + l16;
        const float* xr = X + (size_t)r * NF + quad * 8;
        #pragma unroll
        for (int kk = 0; kk < 4; ++kk) {
            float4 x0 = *(const float4*)(xr + kk * 32);
            float4 x1 = *(const float4*)(xr + kk * 32 + 4);
            af[m][kk].u[0] = f2bf(x0.x); af[m][kk].u[1] = f2bf(x0.y);
            af[m][kk].u[2] = f2bf(x0.z); af[m][kk].u[3] = f2bf(x0.w);
            af[m][kk].u[4] = f2bf(x1.x); af[m][kk].u[5] = f2bf(x1.y);
            af[m][kk].u[6] = f2bf(x1.z); af[m][kk].u[7] = f2bf(x1.w);
        }
    }

    f32x4 acc[2][8];
    #pragma unroll
    for (int m = 0; m < 2; ++m)
        #pragma unroll
        for (int c = 0; c < 8; ++c) acc[m][c] = (f32x4){0.f, 0.f, 0.f, 0.f};

    #pragma unroll
    for (int c = 0; c < 8; ++c) {
        const unsigned short* wb = &Wt[(c * 16 + l16) * WTS + quad * 8];
        #pragma unroll
        for (int kk = 0; kk < 4; ++kk) {
            union { uint4 q; sh8 v; } bf_;
            bf_.q = *(const uint4*)(wb + kk * 32);
            acc[0][c] = __builtin_amdgcn_mfma_f32_16x16x32_bf16(
                af[0][kk].v, bf_.v, acc[0][c], 0, 0, 0);
            acc[1][c] = __builtin_amdgcn_mfma_f32_16x16x32_bf16(
                af[1][kk].v, bf_.v, acc[1][c], 0, 0, 0);
        }
    }

    float psum[8];
    #pragma unroll
    for (int c = 0; c < 8; ++c) psum[c] = 0.0f;

    #pragma unroll
    for (int c = 0; c < 8; ++c) {
        int col = c * 16 + l16;
        float bias = b[col];
        #pragma unroll
        for (int m = 0; m < 2; ++m) {
            #pragma unroll
            for (int reg = 0; reg < 4; ++reg) {
                int r = rowA0 + m * 16 + quad * 4 + reg;
                float v = fmaxf(acc[m][c][reg] + bias, 0.0f);
                Y[(size_t)r * NF + col] = v;
                psum[c] += v;
            }
        }
    }

    if (fuse) {
        // deterministic cross-quad reduction, then cross-wave LDS tree
        #pragma unroll
        for (int c = 0; c < 8; ++c) {
            float v = psum[c];
            v += __shfl_xor(v, 16);
            v += __shfl_xor(v, 32);
            if (lane < 16) part[wid * NF + c * 16 + lane] = v;
        }
        __syncthreads();
        if (t < NF) {
            float s = part[t] + part[NF + t] + part[2 * NF + t]
                    + part[3 * NF + t];
            partial[(size_t)blockIdx.x * NF + t] = s;
        }
    }
}

// ---------------------------------------------------------------------------
// Readout: per graph, mean-pool from gemm2 partials (4 blocks/graph) + MLP.
// ---------------------------------------------------------------------------
__global__ __launch_bounds__(128) void readout_kernel(
    const float* __restrict__ partial,   // [BN/128][NF]
    const float* __restrict__ Wr1, const float* __restrict__ br1,
    const float* __restrict__ Wr2, const float* __restrict__ br2,
    float* __restrict__ out)
{
    __shared__ float hsh[NF];
    __shared__ float r1[64];

    int g = blockIdx.x;
    int t = threadIdx.x;

    const float* pg = partial + (size_t)g * 4 * NF;
    float s = 0.0f;
    #pragma unroll
    for (int j = 0; j < 4; ++j) s += pg[j * NF + t];
    hsh[t] = s * (1.0f / (float)NN);
    __syncthreads();

    if (t < 64) {
        float a = br1[t];
        #pragma unroll 8
        for (int k = 0; k < NF; ++k) a += hsh[k] * Wr1[k * 64 + t];
        r1[t] = fmaxf(a, 0.0f);
    }
    __syncthreads();

    if (t < 64) {
        float v = r1[t] * Wr2[t];
        #pragma unroll
        for (int off = 32; off; off >>= 1) v += __shfl_down(v, off);
        if (t == 0) out[g] = v + br2[0];
    }
}

// ---------------------------------------------------------------------------
extern "C" void kernel_launch(void* const* d_in, const int* in_sizes, int n_in,
                              void* d_out, int out_size, void* d_ws, size_t ws_size,
                              hipStream_t stream)
{
    const float* X    = (const float*)d_in[0];
    // d_in[1] = batch (unused; nodes already grouped per graph)
    const int*   ei   = (const int*)d_in[2];
    const float* W1   = (const float*)d_in[3];
    const float* b1   = (const float*)d_in[4];
    const float* W2   = (const float*)d_in[5];
    const float* b2   = (const float*)d_in[6];
    const float* Wr1  = (const float*)d_in[7];
    const float* br1  = (const float*)d_in[8];
    const float* Wr2  = (const float*)d_in[9];
    const float* br2  = (const float*)d_in[10];
    float* out = (float*)d_out;

    const int* src = ei;
    const int* dst = ei + NE;

    // workspace layout
    char* ws = (char*)d_ws;
    float*          dinvr   = (float*)(ws);                          // 256 KB
    int*            ocnt    = (int*)(ws + (size_t)256 * 1024);       // 32 KB
    int*            perm    = (int*)(ws + (size_t)512 * 1024);       // 256 KB
    float*          partial = (float*)(ws + (size_t)768 * 1024);     // 256 KB
    unsigned short* ell     = (unsigned short*)(ws + (size_t)1024 * 1024); // 8 MB
    float*          buf0    = (float*)(ws + (size_t)16384 * 1024);   // 32 MB
    float*          buf1    = (float*)(ws + (size_t)49152 * 1024);   // 32 MB

    // fused adjacency+ELL build; rank-space outputs
    build_ell_fused_kernel<<<NB, 512, 0, stream>>>(src, dst, ell, ocnt, dinvr,
                                                   perm);

    // bf16 w rows (513 * 64 B) + dsh (512 floats) = 34,880 B
    const size_t LDSSZ = (size_t)(NN + 1) * QST * 2 + NN * 4;

    // ---- Layer 1 (X gathered via perm into rank space)
    poly_fused_kernel<<<NB * 4, 512, LDSSZ, stream>>>(X, buf0, ell, ocnt,
                                                      dinvr, perm, 1);
    gemm_bias_relu_kernel<<<BN / 128, 256, 0, stream>>>(buf0, W1, b1, buf1,
                                                        partial, 0);

    // ---- Layer 2 (all rank space, fully coalesced)
    poly_fused_kernel<<<NB * 4, 512, LDSSZ, stream>>>(buf1, buf0, ell, ocnt,
                                                      dinvr, perm, 0);
    gemm_bias_relu_kernel<<<BN / 128, 256, 0, stream>>>(buf0, W2, b2, buf1,
                                                        partial, 1);

    // ---- Readout from partials
    readout_kernel<<<NB, 128, 0, stream>>>(partial, Wr1, br1, Wr2, br2, out);
}

// Round 6
// 233.315 us; speedup vs baseline: 1.1129x; 1.0555x over previous
//
#include <hip/hip_runtime.h>
#include <hip/hip_bf16.h>

// Problem constants (match reference)
#define NB 128          // graphs
#define NN 512          // nodes per graph
#define NF 128          // input/hidden feature dim
#define BN (NB*NN)      // 65536 total nodes
#define NE (BN*16)      // 1048576 edges
#define EPG 8192        // edges per graph (N*DEG_AVG)
#define WPR 16          // bitmap words per row (512 bits / 32)
#define ELLW 64         // ELL width (max padded degree)
#define QST 32          // poly w row stride in ushorts (64 B: stride==bank-run)
#define SST 72          // build-kernel ELL staging stride
#define WTS 136         // gemm Wt LDS stride in ushorts (272 B, 16-B aligned)

typedef short sh8 __attribute__((ext_vector_type(8)));
typedef float f32x4 __attribute__((ext_vector_type(4)));

static __device__ __forceinline__ unsigned short f2bf(float f) {
    unsigned u = __float_as_uint(f);
    u += 0x7fffu + ((u >> 16) & 1u);        // round-to-nearest-even
    return (unsigned short)(u >> 16);
}

// acc += bf16_low(pk)  /  acc += bf16_high(pk) via VOP3P dot2:
// D = S0.x*S1.x + S0.y*S1.y + S2 ; products exact (x1.0), +0 exact ->
// bitwise identical to shift+add, at half the instruction count.
#define DOT2LO(acc_, pk_, one_) \
    asm("v_dot2_f32_bf16 %0, %1, %2, %0" : "+v"(acc_) : "v"(pk_), "v"(one_))

// ---------------------------------------------------------------------------
// Fused adjacency + ELL build, one 1024-thread block per graph.
// R6: the 512-thread version ran at 45.5us with 9% occupancy / 12% VALU —
// pure latency. Critical chains split across a thread PAIR per row:
//   A = t (row, bitmap words 0-7), B = t+512 (same row, words 8-15).
// - degree: two half-popcounts combined via LDS
// - rank: each scans HALF of cs[] with int4 LDS reads (64 pipelined reads
//   vs 512 scalar dependent reads at ~120cy single-outstanding latency)
// - ELL extraction: A emits entries [0, popc_lo), B emits [popc_lo, deg)
//   — concatenation == original sequential order => outputs bit-identical.
// Rows ranked by degree; everything downstream lives in rank space.
// ---------------------------------------------------------------------------
__global__ __launch_bounds__(1024) void build_ell_fused_kernel(
    const int* __restrict__ src, const int* __restrict__ dst,
    unsigned short* __restrict__ ell, int* __restrict__ ocnt,
    float* __restrict__ dinvr, int* __restrict__ perm)
{
    __shared__ unsigned bm[NN * WPR];   // 32 KB; later reused as ELL staging
    __shared__ int cs[NN];              // capped degree by row
    __shared__ int rdeg[NN];            // degree by rank
    __shared__ int irank[NN];           // row -> rank
    __shared__ int half1[NN];           // popc of words 0-7 (uncapped)
    __shared__ int half2[NN];           // popc of words 8-15 (uncapped)
    __shared__ int prk[NN];             // partial rank from scanner A
    int g = blockIdx.x;
    int t = threadIdx.x;                // 0..1023
    int row = t & 511;
    int hb  = t >> 9;                   // 0 = words 0-7, 1 = words 8-15
    int wo  = hb * 8;

    for (int i = t; i < NN * WPR; i += 1024) bm[i] = 0u;
    __syncthreads();

    const int4* sg4 = (const int4*)(src + (size_t)g * EPG);
    const int4* dg4 = (const int4*)(dst + (size_t)g * EPG);
    for (int i = t; i < EPG / 4; i += 1024) {
        int4 s4 = sg4[i];
        int4 d4 = dg4[i];
        int s, d;
        s = s4.x & (NN - 1); d = d4.x & (NN - 1);
        atomicOr(&bm[s * WPR + (d >> 5)], 1u << (d & 31));
        s = s4.y & (NN - 1); d = d4.y & (NN - 1);
        atomicOr(&bm[s * WPR + (d >> 5)], 1u << (d & 31));
        s = s4.z & (NN - 1); d = d4.z & (NN - 1);
        atomicOr(&bm[s * WPR + (d >> 5)], 1u << (d & 31));
        s = s4.w & (NN - 1); d = d4.w & (NN - 1);
        atomicOr(&bm[s * WPR + (d >> 5)], 1u << (d & 31));
    }
    __syncthreads();

    // extract this thread's half-row into registers
    unsigned rw[8];
    #pragma unroll
    for (int w = 0; w < 8; ++w) rw[w] = bm[row * WPR + wo + w];
    int pc = 0;
    #pragma unroll
    for (int w = 0; w < 8; ++w) pc += __popc(rw[w]);
    if (hb) half2[row] = pc; else half1[row] = pc;
    __syncthreads();                    // all bm reads done; halves visible

    if (!hb) {
        int d0 = pc + half2[row];
        if (d0 > ELLW) d0 = ELLW;       // defensive cap (matches original)
        cs[row] = d0;
    }
    __syncthreads();                    // cs visible

    // deterministic rank: ascending by (deg, row). Each pair member scans
    // HALF the rows with int4 LDS reads (broadcast across lanes).
    int deg_r = cs[row];
    {
        const int4* c4 = (const int4*)cs;
        int ib = hb * 64;               // int4 index base: [0,64) or [64,128)
        int pcnt = 0;
        #pragma unroll 8
        for (int ii = 0; ii < 64; ++ii) {
            int4 v = c4[ib + ii];
            int i0 = (ib + ii) * 4;
            pcnt += (v.x < deg_r) || (v.x == deg_r && (i0 + 0) < row);
            pcnt += (v.y < deg_r) || (v.y == deg_r && (i0 + 1) < row);
            pcnt += (v.z < deg_r) || (v.z == deg_r && (i0 + 2) < row);
            pcnt += (v.w < deg_r) || (v.w == deg_r && (i0 + 3) < row);
        }
        if (!hb) prk[row] = pcnt;
        __syncthreads();
        if (hb) {
            int rk = prk[row] + pcnt;
            irank[row] = rk;
            rdeg[rk] = deg_r;
            perm[(size_t)g * NN + rk] = row;
            dinvr[(size_t)g * NN + rk] =
                (deg_r > 0) ? rsqrtf((float)deg_r) : 0.0f;
        }
    }
    __syncthreads();                    // irank/rdeg visible

    if (t < NN / 8) {
        // ascending sort: oct max = last element of the oct
        int m = rdeg[t * 8 + 7];
        ocnt[(size_t)g * (NN / 8) + t] = (m + 3) & ~3;
    }

    // ELL staging (rank order, RANK-mapped entries) + coalesced writeout.
    // A emits low-half entries from c=0; B emits high-half from c=popc_lo;
    // concatenation reproduces the original sequential entry order.
    unsigned short* els = (unsigned short*)bm;
    int rk = irank[row];
    for (int qtr = 0; qtr < 4; ++qtr) {
        if ((rk >> 7) == qtr) {
            unsigned short* er = &els[(rk & 127) * SST];
            int c = hb ? half1[row] : 0;
            #pragma unroll
            for (int w = 0; w < 8; ++w) {
                unsigned bits = rw[w];
                while (bits) {
                    int j = __ffs(bits) - 1;
                    bits &= bits - 1;
                    if (c < ELLW) er[c] = (unsigned short)irank[(wo + w) * 32 + j];
                    ++c;
                }
            }
            if (hb) {                   // B also pads the tail
                if (c > ELLW) c = ELLW;
                for (int p = c; p < ELLW; ++p) er[p] = (unsigned short)NN;
            }
        }
        __syncthreads();
        unsigned short* outb = ell + ((size_t)g * NN + qtr * 128) * ELLW;
        {
            int r2 = t >> 3, sg2 = t & 7;
            uint4 v = *(const uint4*)&els[r2 * SST + sg2 * 8];
            *(uint4*)&outb[(size_t)r2 * ELLW + sg2 * 8] = v;
        }
        __syncthreads();
    }
}

// ---------------------------------------------------------------------------
// Fused 3-hop poly conv in RANK space, one block per (graph, feature-QUARTER).
// grid = 512 blocks of 512 thr, 34.9 KB LDS -> 2 blocks/CU.
// (unchanged from R5 — bank-uniform cooperative gather, 4 lanes per 64-B row)
// ---------------------------------------------------------------------------
__global__ __launch_bounds__(512, 4) void poly_fused_kernel(
    const float* __restrict__ xin,            // [BN, NF]
    float* __restrict__ accout,               // [BN, NF] rank space
    const unsigned short* __restrict__ ell,   // [BN][ELLW] rank entries
    const int* __restrict__ ocnt,             // [BN/8] padded oct counts
    const float* __restrict__ dinvr,          // [BN] rank-indexed
    const int* __restrict__ perm,             // [BN] rank -> row
    int permuteIn)
{
    extern __shared__ float lds[];
    unsigned short* w = (unsigned short*)lds;        // (NN+1) rows * QST
    float* dsh = lds + ((NN + 1) * QST * 2) / 4;     // NN floats

    int b = blockIdx.x;
    int g = b & 127;                     // graph (same-graph blocks -> same XCD)
    int q = b >> 7;                      // feature quarter (32 feats)
    int t = threadIdx.x;                 // 0..511
    int wid = t >> 6;                    // 0..7
    int qd  = (t >> 2) & 15;             // quad-in-wave 0..15
    int fbq = t & 3;                     // 16-B chunk 0..3 (8 feats)

    unsigned one_lo = 0x00003F80u;       // bf16x2 (1.0, 0.0)
    unsigned one_hi = 0x3F800000u;       // bf16x2 (0.0, 1.0)

    if (t < NN) dsh[t] = dinvr[(size_t)g * NN + t];
    if (t < QST) w[NN * QST + t] = 0;    // zero sentinel row (bf16 0)

    // 4 passes of 128 ranks; wave handles 16 consecutive ranks (= 2 octs)
    // per pass. Passes 2,3 flip wave order for load balance.
    int rnk[4];
    #pragma unroll
    for (int x = 0; x < 4; ++x) {
        int wl = (x >= 2) ? (7 - wid) : wid;
        rnk[x] = x * 128 + wl * 16 + qd;
    }

    // wave-uniform padded counts: the wave's 16 ranks span octs ob, ob+1
    const int* oc = ocnt + (size_t)g * (NN / 8);
    int co[4];
    #pragma unroll
    for (int x = 0; x < 4; ++x) {
        int ob = (rnk[x] - qd) >> 3;
        co[x] = __builtin_amdgcn_readfirstlane(max(oc[ob], oc[ob + 1]));
    }

    // input row per pass: perm'd for layer 1, identity (coalesced) else
    int px[4];
    if (permuteIn) {
        const int* pmg = perm + (size_t)g * NN;
        #pragma unroll
        for (int x = 0; x < 4; ++x) px[x] = pmg[rnk[x]];
    } else {
        #pragma unroll
        for (int x = 0; x < 4; ++x) px[x] = rnk[x];
    }

    const float* xg = xin + (size_t)g * NN * NF + q * 32 + fbq * 8;

    float acc[4][8];
    #pragma unroll
    for (int x = 0; x < 4; ++x) {
        int row = px[x];
        float4 a0 = *(const float4*)&xg[(size_t)row * NF];
        float4 a1 = *(const float4*)&xg[(size_t)row * NF + 4];
        acc[x][0] = a0.x; acc[x][1] = a0.y; acc[x][2] = a0.z; acc[x][3] = a0.w;
        acc[x][4] = a1.x; acc[x][5] = a1.y; acc[x][6] = a1.z; acc[x][7] = a1.w;
    }

    __syncthreads();                     // dsh + sentinel ready

    #pragma unroll
    for (int x = 0; x < 4; ++x) {
        float di = dsh[rnk[x]];
        unsigned pk[4];
        #pragma unroll
        for (int k = 0; k < 4; ++k) {
            unsigned lo = (unsigned)f2bf(di * acc[x][2 * k]);
            unsigned hi = (unsigned)f2bf(di * acc[x][2 * k + 1]);
            pk[k] = lo | (hi << 16);
        }
        *(uint4*)&w[rnk[x] * QST + fbq * 8] = make_uint4(pk[0], pk[1], pk[2], pk[3]);
    }
    __syncthreads();                     // w init ready

    for (int hop = 0; hop < 3; ++hop) {
        unsigned pst[4][4];              // staged bf16x2 packs per pass
        #pragma unroll
        for (int x = 0; x < 4; ++x) {
            const unsigned short* el =
                ell + ((size_t)g * NN + rnk[x]) * ELLW;
            int cnt = co[x];
            float s[8];
            #pragma unroll
            for (int k = 0; k < 8; ++k) s[k] = 0.0f;

            ushort4 cur = *(const ushort4*)el;     // quad-uniform load
            for (int p = 0; p < cnt; p += 4) {
                ushort4 nxt = cur;
                if (p + 4 < cnt) nxt = *(const ushort4*)(el + p + 4);
                uint4 v0 = *(const uint4*)&w[(int)cur.x * QST + fbq * 8];
                uint4 v1 = *(const uint4*)&w[(int)cur.y * QST + fbq * 8];
                uint4 v2 = *(const uint4*)&w[(int)cur.z * QST + fbq * 8];
                uint4 v3 = *(const uint4*)&w[(int)cur.w * QST + fbq * 8];
                unsigned d[4][4] = {{v0.x, v0.y, v0.z, v0.w},
                                    {v1.x, v1.y, v1.z, v1.w},
                                    {v2.x, v2.y, v2.z, v2.w},
                                    {v3.x, v3.y, v3.z, v3.w}};
                #pragma unroll
                for (int n = 0; n < 4; ++n) {
                    #pragma unroll
                    for (int k = 0; k < 4; ++k) {
                        DOT2LO(s[2 * k],     d[n][k], one_lo);
                        DOT2LO(s[2 * k + 1], d[n][k], one_hi);
                    }
                }
                cur = nxt;
            }

            // fold into acc + pack NOW (dsh is stable): staging = 4 uints
            float di = dsh[rnk[x]];
            #pragma unroll
            for (int k = 0; k < 4; ++k) {
                float zlo = di * s[2 * k];
                float zhi = di * s[2 * k + 1];
                acc[x][2 * k]     += zlo;
                acc[x][2 * k + 1] += zhi;
                unsigned lo = (unsigned)f2bf(di * zlo);
                unsigned hi = (unsigned)f2bf(di * zhi);
                pst[x][k] = lo | (hi << 16);
            }
        }
        __syncthreads();                 // all reads of old w done
        #pragma unroll
        for (int x = 0; x < 4; ++x) {
            *(uint4*)&w[rnk[x] * QST + fbq * 8] =
                make_uint4(pst[x][0], pst[x][1], pst[x][2], pst[x][3]);
        }
        __syncthreads();                 // new w visible
    }

    // coalesced write at rank positions
    float* og = accout + (size_t)g * NN * NF + q * 32 + fbq * 8;
    #pragma unroll
    for (int x = 0; x < 4; ++x) {
        int rr = rnk[x];
        *(float4*)&og[(size_t)rr * NF] =
            make_float4(acc[x][0], acc[x][1], acc[x][2], acc[x][3]);
        *(float4*)&og[(size_t)rr * NF + 4] =
            make_float4(acc[x][4], acc[x][5], acc[x][6], acc[x][7]);
    }
}

// ---------------------------------------------------------------------------
// MFMA bf16 GEMM: Y[65536,128] = relu(bf16(X) @ bf16(W) + b), optional fused
// deterministic mean-pool partials. (unchanged)
// ---------------------------------------------------------------------------
__global__ __launch_bounds__(256, 2) void gemm_bias_relu_kernel(
    const float* __restrict__ X, const float* __restrict__ W,
    const float* __restrict__ b, float* __restrict__ Y,
    float* __restrict__ partial, int fuse)
{
    __shared__ __align__(16) unsigned short Wt[NF * WTS];  // [n][k] bf16
    __shared__ float part[4 * NF];

    int t = threadIdx.x;

    // stage Wt = W^T in bf16
    for (int i = t; i < NF * NF / 4; i += 256) {
        int k = i >> 5;                 // W row
        int n4 = (i & 31) * 4;          // W col group
        float4 wv = ((const float4*)W)[i];
        Wt[(n4 + 0) * WTS + k] = f2bf(wv.x);
        Wt[(n4 + 1) * WTS + k] = f2bf(wv.y);
        Wt[(n4 + 2) * WTS + k] = f2bf(wv.z);
        Wt[(n4 + 3) * WTS + k] = f2bf(wv.w);
    }
    __syncthreads();

    int lane = t & 63;
    int wid  = t >> 6;                  // 0..3
    int quad = lane >> 4;               // 0..3
    int l16  = lane & 15;
    int rowA0 = blockIdx.x * 128 + wid * 32;

    // A fragments: af[m][kk], m in {0,1} (row halves), kk = K-step
    union { unsigned short u[8]; sh8 v; } af[2][4];
    #pragma unroll
    for (int m = 0; m < 2; ++m) {
        int r = rowA0 + m * 16 + l16;
        const float* xr = X + (size_t)r * NF + quad * 8;
        #pragma unroll
        for (int kk = 0; kk < 4; ++kk) {
            float4 x0 = *(const float4*)(xr + kk * 32);
            float4 x1 = *(const float4*)(xr + kk * 32 + 4);
            af[m][kk].u[0] = f2bf(x0.x); af[m][kk].u[1] = f2bf(x0.y);
            af[m][kk].u[2] = f2bf(x0.z); af[m][kk].u[3] = f2bf(x0.w);
            af[m][kk].u[4] = f2bf(x1.x); af[m][kk].u[5] = f2bf(x1.y);
            af[m][kk].u[6] = f2bf(x1.z); af[m][kk].u[7] = f2bf(x1.w);
        }
    }

    f32x4 acc[2][8];
    #pragma unroll
    for (int m = 0; m < 2; ++m)
        #pragma unroll
        for (int c = 0; c < 8; ++c) acc[m][c] = (f32x4){0.f, 0.f, 0.f, 0.f};

    #pragma unroll
    for (int c = 0; c < 8; ++c) {
        const unsigned short* wb = &Wt[(c * 16 + l16) * WTS + quad * 8];
        #pragma unroll
        for (int kk = 0; kk < 4; ++kk) {
            union { uint4 q; sh8 v; } bf_;
            bf_.q = *(const uint4*)(wb + kk * 32);
            acc[0][c] = __builtin_amdgcn_mfma_f32_16x16x32_bf16(
                af[0][kk].v, bf_.v, acc[0][c], 0, 0, 0);
            acc[1][c] = __builtin_amdgcn_mfma_f32_16x16x32_bf16(
                af[1][kk].v, bf_.v, acc[1][c], 0, 0, 0);
        }
    }

    float psum[8];
    #pragma unroll
    for (int c = 0; c < 8; ++c) psum[c] = 0.0f;

    #pragma unroll
    for (int c = 0; c < 8; ++c) {
        int col = c * 16 + l16;
        float bias = b[col];
        #pragma unroll
        for (int m = 0; m < 2; ++m) {
            #pragma unroll
            for (int reg = 0; reg < 4; ++reg) {
                int r = rowA0 + m * 16 + quad * 4 + reg;
                float v = fmaxf(acc[m][c][reg] + bias, 0.0f);
                Y[(size_t)r * NF + col] = v;
                psum[c] += v;
            }
        }
    }

    if (fuse) {
        // deterministic cross-quad reduction, then cross-wave LDS tree
        #pragma unroll
        for (int c = 0; c < 8; ++c) {
            float v = psum[c];
            v += __shfl_xor(v, 16);
            v += __shfl_xor(v, 32);
            if (lane < 16) part[wid * NF + c * 16 + lane] = v;
        }
        __syncthreads();
        if (t < NF) {
            float s = part[t] + part[NF + t] + part[2 * NF + t]
                    + part[3 * NF + t];
            partial[(size_t)blockIdx.x * NF + t] = s;
        }
    }
}

// ---------------------------------------------------------------------------
// Readout: per graph, mean-pool from gemm2 partials (4 blocks/graph) + MLP.
// ---------------------------------------------------------------------------
__global__ __launch_bounds__(128) void readout_kernel(
    const float* __restrict__ partial,   // [BN/128][NF]
    const float* __restrict__ Wr1, const float* __restrict__ br1,
    const float* __restrict__ Wr2, const float* __restrict__ br2,
    float* __restrict__ out)
{
    __shared__ float hsh[NF];
    __shared__ float r1[64];

    int g = blockIdx.x;
    int t = threadIdx.x;

    const float* pg = partial + (size_t)g * 4 * NF;
    float s = 0.0f;
    #pragma unroll
    for (int j = 0; j < 4; ++j) s += pg[j * NF + t];
    hsh[t] = s * (1.0f / (float)NN);
    __syncthreads();

    if (t < 64) {
        float a = br1[t];
        #pragma unroll 8
        for (int k = 0; k < NF; ++k) a += hsh[k] * Wr1[k * 64 + t];
        r1[t] = fmaxf(a, 0.0f);
    }
    __syncthreads();

    if (t < 64) {
        float v = r1[t] * Wr2[t];
        #pragma unroll
        for (int off = 32; off; off >>= 1) v += __shfl_down(v, off);
        if (t == 0) out[g] = v + br2[0];
    }
}

// ---------------------------------------------------------------------------
extern "C" void kernel_launch(void* const* d_in, const int* in_sizes, int n_in,
                              void* d_out, int out_size, void* d_ws, size_t ws_size,
                              hipStream_t stream)
{
    const float* X    = (const float*)d_in[0];
    // d_in[1] = batch (unused; nodes already grouped per graph)
    const int*   ei   = (const int*)d_in[2];
    const float* W1   = (const float*)d_in[3];
    const float* b1   = (const float*)d_in[4];
    const float* W2   = (const float*)d_in[5];
    const float* b2   = (const float*)d_in[6];
    const float* Wr1  = (const float*)d_in[7];
    const float* br1  = (const float*)d_in[8];
    const float* Wr2  = (const float*)d_in[9];
    const float* br2  = (const float*)d_in[10];
    float* out = (float*)d_out;

    const int* src = ei;
    const int* dst = ei + NE;

    // workspace layout
    char* ws = (char*)d_ws;
    float*          dinvr   = (float*)(ws);                          // 256 KB
    int*            ocnt    = (int*)(ws + (size_t)256 * 1024);       // 32 KB
    int*            perm    = (int*)(ws + (size_t)512 * 1024);       // 256 KB
    float*          partial = (float*)(ws + (size_t)768 * 1024);     // 256 KB
    unsigned short* ell     = (unsigned short*)(ws + (size_t)1024 * 1024); // 8 MB
    float*          buf0    = (float*)(ws + (size_t)16384 * 1024);   // 32 MB
    float*          buf1    = (float*)(ws + (size_t)49152 * 1024);   // 32 MB

    // fused adjacency+ELL build; rank-space outputs (1024-thread blocks)
    build_ell_fused_kernel<<<NB, 1024, 0, stream>>>(src, dst, ell, ocnt, dinvr,
                                                    perm);

    // bf16 w rows (513 * 64 B) + dsh (512 floats) = 34,880 B
    const size_t LDSSZ = (size_t)(NN + 1) * QST * 2 + NN * 4;

    // ---- Layer 1 (X gathered via perm into rank space)
    poly_fused_kernel<<<NB * 4, 512, LDSSZ, stream>>>(X, buf0, ell, ocnt,
                                                      dinvr, perm, 1);
    gemm_bias_relu_kernel<<<BN / 128, 256, 0, stream>>>(buf0, W1, b1, buf1,
                                                        partial, 0);

    // ---- Layer 2 (all rank space, fully coalesced)
    poly_fused_kernel<<<NB * 4, 512, LDSSZ, stream>>>(buf1, buf0, ell, ocnt,
                                                      dinvr, perm, 0);
    gemm_bias_relu_kernel<<<BN / 128, 256, 0, stream>>>(buf0, W2, b2, buf1,
                                                        partial, 1);

    // ---- Readout from partials
    readout_kernel<<<NB, 128, 0, stream>>>(partial, Wr1, br1, Wr2, br2, out);
}

// Round 7
// 222.728 us; speedup vs baseline: 1.1658x; 1.0475x over previous
//
#include <hip/hip_runtime.h>
#include <hip/hip_bf16.h>

// Problem constants (match reference)
#define NB 128          // graphs
#define NN 512          // nodes per graph
#define NF 128          // input/hidden feature dim
#define BN (NB*NN)      // 65536 total nodes
#define NE (BN*16)      // 1048576 edges
#define EPG 8192        // edges per graph (N*DEG_AVG)
#define WPR 16          // bitmap words per row (512 bits / 32)
#define ELLW 64         // ELL width (max padded degree)
#define QST 32          // poly w row stride in ushorts (64 B: stride==bank-run)
#define SST 72          // build-kernel ELL staging stride
#define WTS 136         // gemm Wt LDS stride in ushorts (272 B, 16-B aligned)

typedef short sh8 __attribute__((ext_vector_type(8)));
typedef float f32x4 __attribute__((ext_vector_type(4)));

static __device__ __forceinline__ unsigned short f2bf(float f) {
    unsigned u = __float_as_uint(f);
    u += 0x7fffu + ((u >> 16) & 1u);        // round-to-nearest-even
    return (unsigned short)(u >> 16);
}

// acc += bf16_low(pk)  /  acc += bf16_high(pk) via VOP3P dot2:
// D = S0.x*S1.x + S0.y*S1.y + S2 ; products exact (x1.0), +0 exact ->
// bitwise identical to shift+add, at half the instruction count.
#define DOT2LO(acc_, pk_, one_) \
    asm("v_dot2_f32_bf16 %0, %1, %2, %0" : "+v"(acc_) : "v"(pk_), "v"(one_))

// ---------------------------------------------------------------------------
// Fused adjacency + ELL build, one 1024-thread block per graph.
// (unchanged from R6 — pair-split critical chains, bit-identical outputs)
// ---------------------------------------------------------------------------
__global__ __launch_bounds__(1024) void build_ell_fused_kernel(
    const int* __restrict__ src, const int* __restrict__ dst,
    unsigned short* __restrict__ ell, int* __restrict__ ocnt,
    float* __restrict__ dinvr, int* __restrict__ perm)
{
    __shared__ unsigned bm[NN * WPR];   // 32 KB; later reused as ELL staging
    __shared__ int cs[NN];              // capped degree by row
    __shared__ int rdeg[NN];            // degree by rank
    __shared__ int irank[NN];           // row -> rank
    __shared__ int half1[NN];           // popc of words 0-7 (uncapped)
    __shared__ int half2[NN];           // popc of words 8-15 (uncapped)
    __shared__ int prk[NN];             // partial rank from scanner A
    int g = blockIdx.x;
    int t = threadIdx.x;                // 0..1023
    int row = t & 511;
    int hb  = t >> 9;                   // 0 = words 0-7, 1 = words 8-15
    int wo  = hb * 8;

    for (int i = t; i < NN * WPR; i += 1024) bm[i] = 0u;
    __syncthreads();

    const int4* sg4 = (const int4*)(src + (size_t)g * EPG);
    const int4* dg4 = (const int4*)(dst + (size_t)g * EPG);
    for (int i = t; i < EPG / 4; i += 1024) {
        int4 s4 = sg4[i];
        int4 d4 = dg4[i];
        int s, d;
        s = s4.x & (NN - 1); d = d4.x & (NN - 1);
        atomicOr(&bm[s * WPR + (d >> 5)], 1u << (d & 31));
        s = s4.y & (NN - 1); d = d4.y & (NN - 1);
        atomicOr(&bm[s * WPR + (d >> 5)], 1u << (d & 31));
        s = s4.z & (NN - 1); d = d4.z & (NN - 1);
        atomicOr(&bm[s * WPR + (d >> 5)], 1u << (d & 31));
        s = s4.w & (NN - 1); d = d4.w & (NN - 1);
        atomicOr(&bm[s * WPR + (d >> 5)], 1u << (d & 31));
    }
    __syncthreads();

    // extract this thread's half-row into registers
    unsigned rw[8];
    #pragma unroll
    for (int w = 0; w < 8; ++w) rw[w] = bm[row * WPR + wo + w];
    int pc = 0;
    #pragma unroll
    for (int w = 0; w < 8; ++w) pc += __popc(rw[w]);
    if (hb) half2[row] = pc; else half1[row] = pc;
    __syncthreads();                    // all bm reads done; halves visible

    if (!hb) {
        int d0 = pc + half2[row];
        if (d0 > ELLW) d0 = ELLW;       // defensive cap (matches original)
        cs[row] = d0;
    }
    __syncthreads();                    // cs visible

    // deterministic rank: ascending by (deg, row). Each pair member scans
    // HALF of cs[] with int4 LDS reads (pipelined, broadcast-friendly).
    int deg_r = cs[row];
    {
        const int4* c4 = (const int4*)cs;
        int ib = hb * 64;               // int4 index base: [0,64) or [64,128)
        int pcnt = 0;
        #pragma unroll 8
        for (int ii = 0; ii < 64; ++ii) {
            int4 v = c4[ib + ii];
            int i0 = (ib + ii) * 4;
            pcnt += (v.x < deg_r) || (v.x == deg_r && (i0 + 0) < row);
            pcnt += (v.y < deg_r) || (v.y == deg_r && (i0 + 1) < row);
            pcnt += (v.z < deg_r) || (v.z == deg_r && (i0 + 2) < row);
            pcnt += (v.w < deg_r) || (v.w == deg_r && (i0 + 3) < row);
        }
        if (!hb) prk[row] = pcnt;
        __syncthreads();
        if (hb) {
            int rk = prk[row] + pcnt;
            irank[row] = rk;
            rdeg[rk] = deg_r;
            perm[(size_t)g * NN + rk] = row;
            dinvr[(size_t)g * NN + rk] =
                (deg_r > 0) ? rsqrtf((float)deg_r) : 0.0f;
        }
    }
    __syncthreads();                    // irank/rdeg visible

    if (t < NN / 8) {
        // ascending sort: oct max = last element of the oct
        int m = rdeg[t * 8 + 7];
        ocnt[(size_t)g * (NN / 8) + t] = (m + 3) & ~3;
    }

    // ELL staging (rank order, RANK-mapped entries) + coalesced writeout.
    // A emits low-half entries from c=0; B emits high-half from c=popc_lo;
    // concatenation reproduces the original sequential entry order.
    unsigned short* els = (unsigned short*)bm;
    int rk = irank[row];
    for (int qtr = 0; qtr < 4; ++qtr) {
        if ((rk >> 7) == qtr) {
            unsigned short* er = &els[(rk & 127) * SST];
            int c = hb ? half1[row] : 0;
            #pragma unroll
            for (int w = 0; w < 8; ++w) {
                unsigned bits = rw[w];
                while (bits) {
                    int j = __ffs(bits) - 1;
                    bits &= bits - 1;
                    if (c < ELLW) er[c] = (unsigned short)irank[(wo + w) * 32 + j];
                    ++c;
                }
            }
            if (hb) {                   // B also pads the tail
                if (c > ELLW) c = ELLW;
                for (int p = c; p < ELLW; ++p) er[p] = (unsigned short)NN;
            }
        }
        __syncthreads();
        unsigned short* outb = ell + ((size_t)g * NN + qtr * 128) * ELLW;
        {
            int r2 = t >> 3, sg2 = t & 7;
            uint4 v = *(const uint4*)&els[r2 * SST + sg2 * 8];
            *(uint4*)&outb[(size_t)r2 * ELLW + sg2 * 8] = v;
        }
        __syncthreads();
    }
}

// ---------------------------------------------------------------------------
// Fused 3-hop poly conv in RANK space, one block per (graph, feature-QUARTER).
// grid = 512 blocks of 512 thr, 34.9 KB LDS. (R5 bank-uniform gather.)
// R7: accout is now BF16 (ushort). The downstream GEMM rounds its input to
// bf16 anyway (f2bf before MFMA) — rounding at the producer is bit-identical
// and halves the write+read traffic at the poly->gemm seam.
// ---------------------------------------------------------------------------
__global__ __launch_bounds__(512, 4) void poly_fused_kernel(
    const float* __restrict__ xin,            // [BN, NF] f32
    unsigned short* __restrict__ accout,      // [BN, NF] bf16, rank space
    const unsigned short* __restrict__ ell,   // [BN][ELLW] rank entries
    const int* __restrict__ ocnt,             // [BN/8] padded oct counts
    const float* __restrict__ dinvr,          // [BN] rank-indexed
    const int* __restrict__ perm,             // [BN] rank -> row
    int permuteIn)
{
    extern __shared__ float lds[];
    unsigned short* w = (unsigned short*)lds;        // (NN+1) rows * QST
    float* dsh = lds + ((NN + 1) * QST * 2) / 4;     // NN floats

    int b = blockIdx.x;
    int g = b & 127;                     // graph (same-graph blocks -> same XCD)
    int q = b >> 7;                      // feature quarter (32 feats)
    int t = threadIdx.x;                 // 0..511
    int wid = t >> 6;                    // 0..7
    int qd  = (t >> 2) & 15;             // quad-in-wave 0..15
    int fbq = t & 3;                     // 16-B chunk 0..3 (8 feats)

    unsigned one_lo = 0x00003F80u;       // bf16x2 (1.0, 0.0)
    unsigned one_hi = 0x3F800000u;       // bf16x2 (0.0, 1.0)

    if (t < NN) dsh[t] = dinvr[(size_t)g * NN + t];
    if (t < QST) w[NN * QST + t] = 0;    // zero sentinel row (bf16 0)

    // 4 passes of 128 ranks; wave handles 16 consecutive ranks (= 2 octs)
    // per pass. Passes 2,3 flip wave order for load balance.
    int rnk[4];
    #pragma unroll
    for (int x = 0; x < 4; ++x) {
        int wl = (x >= 2) ? (7 - wid) : wid;
        rnk[x] = x * 128 + wl * 16 + qd;
    }

    // wave-uniform padded counts: the wave's 16 ranks span octs ob, ob+1
    const int* oc = ocnt + (size_t)g * (NN / 8);
    int co[4];
    #pragma unroll
    for (int x = 0; x < 4; ++x) {
        int ob = (rnk[x] - qd) >> 3;
        co[x] = __builtin_amdgcn_readfirstlane(max(oc[ob], oc[ob + 1]));
    }

    // input row per pass: perm'd for layer 1, identity (coalesced) else
    int px[4];
    if (permuteIn) {
        const int* pmg = perm + (size_t)g * NN;
        #pragma unroll
        for (int x = 0; x < 4; ++x) px[x] = pmg[rnk[x]];
    } else {
        #pragma unroll
        for (int x = 0; x < 4; ++x) px[x] = rnk[x];
    }

    const float* xg = xin + (size_t)g * NN * NF + q * 32 + fbq * 8;

    float acc[4][8];
    #pragma unroll
    for (int x = 0; x < 4; ++x) {
        int row = px[x];
        float4 a0 = *(const float4*)&xg[(size_t)row * NF];
        float4 a1 = *(const float4*)&xg[(size_t)row * NF + 4];
        acc[x][0] = a0.x; acc[x][1] = a0.y; acc[x][2] = a0.z; acc[x][3] = a0.w;
        acc[x][4] = a1.x; acc[x][5] = a1.y; acc[x][6] = a1.z; acc[x][7] = a1.w;
    }

    __syncthreads();                     // dsh + sentinel ready

    #pragma unroll
    for (int x = 0; x < 4; ++x) {
        float di = dsh[rnk[x]];
        unsigned pk[4];
        #pragma unroll
        for (int k = 0; k < 4; ++k) {
            unsigned lo = (unsigned)f2bf(di * acc[x][2 * k]);
            unsigned hi = (unsigned)f2bf(di * acc[x][2 * k + 1]);
            pk[k] = lo | (hi << 16);
        }
        *(uint4*)&w[rnk[x] * QST + fbq * 8] = make_uint4(pk[0], pk[1], pk[2], pk[3]);
    }
    __syncthreads();                     // w init ready

    for (int hop = 0; hop < 3; ++hop) {
        unsigned pst[4][4];              // staged bf16x2 packs per pass
        #pragma unroll
        for (int x = 0; x < 4; ++x) {
            const unsigned short* el =
                ell + ((size_t)g * NN + rnk[x]) * ELLW;
            int cnt = co[x];
            float s[8];
            #pragma unroll
            for (int k = 0; k < 8; ++k) s[k] = 0.0f;

            ushort4 cur = *(const ushort4*)el;     // quad-uniform load
            for (int p = 0; p < cnt; p += 4) {
                ushort4 nxt = cur;
                if (p + 4 < cnt) nxt = *(const ushort4*)(el + p + 4);
                uint4 v0 = *(const uint4*)&w[(int)cur.x * QST + fbq * 8];
                uint4 v1 = *(const uint4*)&w[(int)cur.y * QST + fbq * 8];
                uint4 v2 = *(const uint4*)&w[(int)cur.z * QST + fbq * 8];
                uint4 v3 = *(const uint4*)&w[(int)cur.w * QST + fbq * 8];
                unsigned d[4][4] = {{v0.x, v0.y, v0.z, v0.w},
                                    {v1.x, v1.y, v1.z, v1.w},
                                    {v2.x, v2.y, v2.z, v2.w},
                                    {v3.x, v3.y, v3.z, v3.w}};
                #pragma unroll
                for (int n = 0; n < 4; ++n) {
                    #pragma unroll
                    for (int k = 0; k < 4; ++k) {
                        DOT2LO(s[2 * k],     d[n][k], one_lo);
                        DOT2LO(s[2 * k + 1], d[n][k], one_hi);
                    }
                }
                cur = nxt;
            }

            // fold into acc + pack NOW (dsh is stable): staging = 4 uints
            float di = dsh[rnk[x]];
            #pragma unroll
            for (int k = 0; k < 4; ++k) {
                float zlo = di * s[2 * k];
                float zhi = di * s[2 * k + 1];
                acc[x][2 * k]     += zlo;
                acc[x][2 * k + 1] += zhi;
                unsigned lo = (unsigned)f2bf(di * zlo);
                unsigned hi = (unsigned)f2bf(di * zhi);
                pst[x][k] = lo | (hi << 16);
            }
        }
        __syncthreads();                 // all reads of old w done
        #pragma unroll
        for (int x = 0; x < 4; ++x) {
            *(uint4*)&w[rnk[x] * QST + fbq * 8] =
                make_uint4(pst[x][0], pst[x][1], pst[x][2], pst[x][3]);
        }
        __syncthreads();                 // new w visible
    }

    // coalesced bf16 write at rank positions (16 B per pass per thread).
    // f2bf here == the rounding gemm would apply on load -> bit-identical.
    unsigned short* og = accout + (size_t)g * NN * NF + q * 32 + fbq * 8;
    #pragma unroll
    for (int x = 0; x < 4; ++x) {
        int rr = rnk[x];
        uint4 pk;
        pk.x = (unsigned)f2bf(acc[x][0]) | ((unsigned)f2bf(acc[x][1]) << 16);
        pk.y = (unsigned)f2bf(acc[x][2]) | ((unsigned)f2bf(acc[x][3]) << 16);
        pk.z = (unsigned)f2bf(acc[x][4]) | ((unsigned)f2bf(acc[x][5]) << 16);
        pk.w = (unsigned)f2bf(acc[x][6]) | ((unsigned)f2bf(acc[x][7]) << 16);
        *(uint4*)&og[(size_t)rr * NF] = pk;
    }
}

// ---------------------------------------------------------------------------
// MFMA bf16 GEMM: Y[65536,128] = relu(bf16X @ bf16(W) + b), optional fused
// deterministic mean-pool partials.
// R7: X arrives as BF16 (poly pre-rounds — bit-identical, half the fetch,
// and the 64-f2bf prologue chain is gone). When fuse=1 the Y store is
// skipped entirely: readout consumes only `partial`, so gemm2's Y was
// 33.5 MB of dead HBM write traffic.
// ---------------------------------------------------------------------------
__global__ __launch_bounds__(256, 2) void gemm_bias_relu_kernel(
    const unsigned short* __restrict__ X,   // [BN, NF] bf16
    const float* __restrict__ W,
    const float* __restrict__ b, float* __restrict__ Y,
    float* __restrict__ partial, int fuse)
{
    __shared__ __align__(16) unsigned short Wt[NF * WTS];  // [n][k] bf16
    __shared__ float part[4 * NF];

    int t = threadIdx.x;

    // stage Wt = W^T in bf16
    for (int i = t; i < NF * NF / 4; i += 256) {
        int k = i >> 5;                 // W row
        int n4 = (i & 31) * 4;          // W col group
        float4 wv = ((const float4*)W)[i];
        Wt[(n4 + 0) * WTS + k] = f2bf(wv.x);
        Wt[(n4 + 1) * WTS + k] = f2bf(wv.y);
        Wt[(n4 + 2) * WTS + k] = f2bf(wv.z);
        Wt[(n4 + 3) * WTS + k] = f2bf(wv.w);
    }
    __syncthreads();

    int lane = t & 63;
    int wid  = t >> 6;                  // 0..3
    int quad = lane >> 4;               // 0..3
    int l16  = lane & 15;
    int rowA0 = blockIdx.x * 128 + wid * 32;

    // A fragments: direct bf16 16-B loads (no conversion chain)
    union { uint4 q; sh8 v; } af[2][4];
    #pragma unroll
    for (int m = 0; m < 2; ++m) {
        int r = rowA0 + m * 16 + l16;
        const unsigned short* xr = X + (size_t)r * NF + quad * 8;
        #pragma unroll
        for (int kk = 0; kk < 4; ++kk)
            af[m][kk].q = *(const uint4*)(xr + kk * 32);
    }

    f32x4 acc[2][8];
    #pragma unroll
    for (int m = 0; m < 2; ++m)
        #pragma unroll
        for (int c = 0; c < 8; ++c) acc[m][c] = (f32x4){0.f, 0.f, 0.f, 0.f};

    #pragma unroll
    for (int c = 0; c < 8; ++c) {
        const unsigned short* wb = &Wt[(c * 16 + l16) * WTS + quad * 8];
        #pragma unroll
        for (int kk = 0; kk < 4; ++kk) {
            union { uint4 q; sh8 v; } bf_;
            bf_.q = *(const uint4*)(wb + kk * 32);
            acc[0][c] = __builtin_amdgcn_mfma_f32_16x16x32_bf16(
                af[0][kk].v, bf_.v, acc[0][c], 0, 0, 0);
            acc[1][c] = __builtin_amdgcn_mfma_f32_16x16x32_bf16(
                af[1][kk].v, bf_.v, acc[1][c], 0, 0, 0);
        }
    }

    float psum[8];
    #pragma unroll
    for (int c = 0; c < 8; ++c) psum[c] = 0.0f;

    #pragma unroll
    for (int c = 0; c < 8; ++c) {
        int col = c * 16 + l16;
        float bias = b[col];
        #pragma unroll
        for (int m = 0; m < 2; ++m) {
            #pragma unroll
            for (int reg = 0; reg < 4; ++reg) {
                int r = rowA0 + m * 16 + quad * 4 + reg;
                float v = fmaxf(acc[m][c][reg] + bias, 0.0f);
                if (!fuse) Y[(size_t)r * NF + col] = v;
                psum[c] += v;
            }
        }
    }

    if (fuse) {
        // deterministic cross-quad reduction, then cross-wave LDS tree
        #pragma unroll
        for (int c = 0; c < 8; ++c) {
            float v = psum[c];
            v += __shfl_xor(v, 16);
            v += __shfl_xor(v, 32);
            if (lane < 16) part[wid * NF + c * 16 + lane] = v;
        }
        __syncthreads();
        if (t < NF) {
            float s = part[t] + part[NF + t] + part[2 * NF + t]
                    + part[3 * NF + t];
            partial[(size_t)blockIdx.x * NF + t] = s;
        }
    }
}

// ---------------------------------------------------------------------------
// Readout: per graph, mean-pool from gemm2 partials (4 blocks/graph) + MLP.
// ---------------------------------------------------------------------------
__global__ __launch_bounds__(128) void readout_kernel(
    const float* __restrict__ partial,   // [BN/128][NF]
    const float* __restrict__ Wr1, const float* __restrict__ br1,
    const float* __restrict__ Wr2, const float* __restrict__ br2,
    float* __restrict__ out)
{
    __shared__ float hsh[NF];
    __shared__ float r1[64];

    int g = blockIdx.x;
    int t = threadIdx.x;

    const float* pg = partial + (size_t)g * 4 * NF;
    float s = 0.0f;
    #pragma unroll
    for (int j = 0; j < 4; ++j) s += pg[j * NF + t];
    hsh[t] = s * (1.0f / (float)NN);
    __syncthreads();

    if (t < 64) {
        float a = br1[t];
        #pragma unroll 8
        for (int k = 0; k < NF; ++k) a += hsh[k] * Wr1[k * 64 + t];
        r1[t] = fmaxf(a, 0.0f);
    }
    __syncthreads();

    if (t < 64) {
        float v = r1[t] * Wr2[t];
        #pragma unroll
        for (int off = 32; off; off >>= 1) v += __shfl_down(v, off);
        if (t == 0) out[g] = v + br2[0];
    }
}

// ---------------------------------------------------------------------------
extern "C" void kernel_launch(void* const* d_in, const int* in_sizes, int n_in,
                              void* d_out, int out_size, void* d_ws, size_t ws_size,
                              hipStream_t stream)
{
    const float* X    = (const float*)d_in[0];
    // d_in[1] = batch (unused; nodes already grouped per graph)
    const int*   ei   = (const int*)d_in[2];
    const float* W1   = (const float*)d_in[3];
    const float* b1   = (const float*)d_in[4];
    const float* W2   = (const float*)d_in[5];
    const float* b2   = (const float*)d_in[6];
    const float* Wr1  = (const float*)d_in[7];
    const float* br1  = (const float*)d_in[8];
    const float* Wr2  = (const float*)d_in[9];
    const float* br2  = (const float*)d_in[10];
    float* out = (float*)d_out;

    const int* src = ei;
    const int* dst = ei + NE;

    // workspace layout
    char* ws = (char*)d_ws;
    float*          dinvr   = (float*)(ws);                          // 256 KB
    int*            ocnt    = (int*)(ws + (size_t)256 * 1024);       // 32 KB
    int*            perm    = (int*)(ws + (size_t)512 * 1024);       // 256 KB
    float*          partial = (float*)(ws + (size_t)768 * 1024);     // 256 KB
    unsigned short* ell     = (unsigned short*)(ws + (size_t)1024 * 1024); // 8 MB
    unsigned short* buf0    = (unsigned short*)(ws + (size_t)16384 * 1024); // 16.7 MB bf16
    float*          buf1    = (float*)(ws + (size_t)49152 * 1024);   // 32 MB f32

    // fused adjacency+ELL build; rank-space outputs (1024-thread blocks)
    build_ell_fused_kernel<<<NB, 1024, 0, stream>>>(src, dst, ell, ocnt, dinvr,
                                                    perm);

    // bf16 w rows (513 * 64 B) + dsh (512 floats) = 34,880 B
    const size_t LDSSZ = (size_t)(NN + 1) * QST * 2 + NN * 4;

    // ---- Layer 1 (X gathered via perm into rank space; accout bf16)
    poly_fused_kernel<<<NB * 4, 512, LDSSZ, stream>>>(X, buf0, ell, ocnt,
                                                      dinvr, perm, 1);
    gemm_bias_relu_kernel<<<BN / 128, 256, 0, stream>>>(buf0, W1, b1, buf1,
                                                        partial, 0);

    // ---- Layer 2 (all rank space, fully coalesced; accout bf16)
    poly_fused_kernel<<<NB * 4, 512, LDSSZ, stream>>>(buf1, buf0, ell, ocnt,
                                                      dinvr, perm, 0);
    gemm_bias_relu_kernel<<<BN / 128, 256, 0, stream>>>(buf0, W2, b2, buf1,
                                                        partial, 1);

    // ---- Readout from partials
    readout_kernel<<<NB, 128, 0, stream>>>(partial, Wr1, br1, Wr2, br2, out);
}

// Round 8
// 220.294 us; speedup vs baseline: 1.1787x; 1.0110x over previous
//
#include <hip/hip_runtime.h>
#include <hip/hip_bf16.h>

// Problem constants (match reference)
#define NB 128          // graphs
#define NN 512          // nodes per graph
#define NF 128          // input/hidden feature dim
#define BN (NB*NN)      // 65536 total nodes
#define NE (BN*16)      // 1048576 edges
#define EPG 8192        // edges per graph (N*DEG_AVG)
#define WPR 16          // bitmap words per row (512 bits / 32)
#define ELLW 64         // ELL width (max padded degree)
#define QST 32          // poly w row stride in ushorts (64 B: stride==bank-run)
#define SST 72          // ELL staging stride (ushorts)
#define WTS 136         // gemm Wt LDS stride in ushorts (272 B, 16-B aligned)

typedef short sh8 __attribute__((ext_vector_type(8)));
typedef float f32x4 __attribute__((ext_vector_type(4)));

static __device__ __forceinline__ unsigned short f2bf(float f) {
    unsigned u = __float_as_uint(f);
    u += 0x7fffu + ((u >> 16) & 1u);        // round-to-nearest-even
    return (unsigned short)(u >> 16);
}

// acc += bf16_low(pk)  /  acc += bf16_high(pk) via VOP3P dot2 (exact).
#define DOT2LO(acc_, pk_, one_) \
    asm("v_dot2_f32_bf16 %0, %1, %2, %0" : "+v"(acc_) : "v"(pk_), "v"(one_))

// ---------------------------------------------------------------------------
// R8 build split, stage A: edge scatter -> per-quarter LDS bitmap -> global.
// 512 blocks (graph, row-quarter) x 256 thr: 4x fewer LDS atomics per DS
// pipe than the fused 128-block version, full CU coverage, coalesced dump.
// ---------------------------------------------------------------------------
__global__ __launch_bounds__(256) void scatter_bitmap_kernel(
    const int* __restrict__ src, const int* __restrict__ dst,
    unsigned* __restrict__ bmg)               // [NB][NN][WPR]
{
    __shared__ unsigned bm[128 * WPR];        // 8 KB: rows qr*128..qr*128+127
    int b = blockIdx.x;
    int g = b >> 2;
    int qr = b & 3;
    int t = threadIdx.x;                      // 0..255

    for (int i = t; i < 128 * WPR; i += 256) bm[i] = 0u;
    __syncthreads();

    const int4* sg4 = (const int4*)(src + (size_t)g * EPG);
    const int4* dg4 = (const int4*)(dst + (size_t)g * EPG);
    int lo = qr << 7;
    for (int i = t; i < EPG / 4; i += 256) {
        int4 s4 = sg4[i];
        int4 d4 = dg4[i];
        int s, d;
        s = s4.x & (NN - 1); d = d4.x & (NN - 1);
        if ((s >> 7) == qr) atomicOr(&bm[(s - lo) * WPR + (d >> 5)], 1u << (d & 31));
        s = s4.y & (NN - 1); d = d4.y & (NN - 1);
        if ((s >> 7) == qr) atomicOr(&bm[(s - lo) * WPR + (d >> 5)], 1u << (d & 31));
        s = s4.z & (NN - 1); d = d4.z & (NN - 1);
        if ((s >> 7) == qr) atomicOr(&bm[(s - lo) * WPR + (d >> 5)], 1u << (d & 31));
        s = s4.w & (NN - 1); d = d4.w & (NN - 1);
        if ((s >> 7) == qr) atomicOr(&bm[(s - lo) * WPR + (d >> 5)], 1u << (d & 31));
    }
    __syncthreads();

    // coalesced 8 KB dump: 512 uint4 / 256 thr = 2 each
    unsigned* outg = bmg + ((size_t)g * NN + (size_t)qr * 128) * WPR;
    #pragma unroll
    for (int i = t; i < 128 * WPR / 4; i += 256)
        *(uint4*)&outg[i * 4] = *(const uint4*)&bm[i * 4];
}

// ---------------------------------------------------------------------------
// R8 build split, stage B: degrees, ranks, ELL extraction + writeout.
// 128 blocks x 1024 thr (thread pair per row: A=words 0-7, B=words 8-15).
// vs R6: bitmap arrives via 2 coalesced uint4 global loads; the 4x
// qtr-serialized ELL staging (8 barriers) becomes ONE full 72 KB LDS staging
// pass + single coalesced 64 KB writeout (~4 barriers total).
// Outputs bit-identical to the fused build (same entry order).
// ---------------------------------------------------------------------------
__global__ __launch_bounds__(1024) void rank_ell_kernel(
    const unsigned* __restrict__ bmg,         // [NB][NN][WPR]
    unsigned short* __restrict__ ell, int* __restrict__ ocnt,
    float* __restrict__ dinvr, int* __restrict__ perm)
{
    __shared__ unsigned short els[NN * SST];  // 73,728 B staging
    __shared__ int cs[NN];                    // capped degree by row
    __shared__ int rdeg[NN];                  // degree by rank
    __shared__ int irank[NN];                 // row -> rank
    __shared__ int half1[NN];                 // popc words 0-7 (uncapped)
    __shared__ int half2[NN];                 // popc words 8-15 (uncapped)
    __shared__ int prk[NN];                   // partial rank from scanner A
    int g = blockIdx.x;
    int t = threadIdx.x;                      // 0..1023
    int row = t & 511;
    int hb  = t >> 9;                         // 0 = words 0-7, 1 = words 8-15
    int wo  = hb * 8;

    // this thread's half-row bitmap: 2 coalesced 16-B loads
    const unsigned* bgr = bmg + ((size_t)g * NN + row) * WPR + wo;
    uint4 q0 = *(const uint4*)bgr;
    uint4 q1 = *(const uint4*)(bgr + 4);
    unsigned rw[8] = {q0.x, q0.y, q0.z, q0.w, q1.x, q1.y, q1.z, q1.w};

    int pc = 0;
    #pragma unroll
    for (int w = 0; w < 8; ++w) pc += __popc(rw[w]);
    if (hb) half2[row] = pc; else half1[row] = pc;
    __syncthreads();

    if (!hb) {
        int d0 = pc + half2[row];
        if (d0 > ELLW) d0 = ELLW;             // defensive cap
        cs[row] = d0;
    }
    __syncthreads();

    // deterministic rank: ascending (deg, row); each pair member scans half
    int deg_r = cs[row];
    {
        const int4* c4 = (const int4*)cs;
        int ib = hb * 64;
        int pcnt = 0;
        #pragma unroll 8
        for (int ii = 0; ii < 64; ++ii) {
            int4 v = c4[ib + ii];
            int i0 = (ib + ii) * 4;
            pcnt += (v.x < deg_r) || (v.x == deg_r && (i0 + 0) < row);
            pcnt += (v.y < deg_r) || (v.y == deg_r && (i0 + 1) < row);
            pcnt += (v.z < deg_r) || (v.z == deg_r && (i0 + 2) < row);
            pcnt += (v.w < deg_r) || (v.w == deg_r && (i0 + 3) < row);
        }
        if (!hb) prk[row] = pcnt;
        __syncthreads();
        if (hb) {
            int rk = prk[row] + pcnt;
            irank[row] = rk;
            rdeg[rk] = deg_r;
            perm[(size_t)g * NN + rk] = row;
            dinvr[(size_t)g * NN + rk] =
                (deg_r > 0) ? rsqrtf((float)deg_r) : 0.0f;
        }
    }
    __syncthreads();                          // irank/rdeg visible

    if (t < NN / 8) {
        int m = rdeg[t * 8 + 7];              // ascending: oct max = last
        ocnt[(size_t)g * (NN / 8) + t] = (m + 3) & ~3;
    }

    // ELL extraction: ALL rows at once into full-size staging.
    // A emits [0, popc_lo), B emits [popc_lo, deg) + pad: original order.
    {
        int rk = irank[row];
        unsigned short* er = &els[rk * SST];
        int c = hb ? half1[row] : 0;
        #pragma unroll
        for (int w = 0; w < 8; ++w) {
            unsigned bits = rw[w];
            while (bits) {
                int j = __ffs(bits) - 1;
                bits &= bits - 1;
                if (c < ELLW) er[c] = (unsigned short)irank[(wo + w) * 32 + j];
                ++c;
            }
        }
        if (hb) {
            if (c > ELLW) c = ELLW;
            for (int p = c; p < ELLW; ++p) er[p] = (unsigned short)NN;
        }
    }
    __syncthreads();                          // staging complete

    // single coalesced writeout: 512 rows x 128 B = 64 KB, 4 iters/thread
    unsigned short* outb = ell + (size_t)g * NN * ELLW;
    for (int idx = t; idx < NN * 8; idx += 1024) {
        int r2 = idx >> 3, sg2 = idx & 7;
        uint4 v = *(const uint4*)&els[r2 * SST + sg2 * 8];
        *(uint4*)&outb[(size_t)r2 * ELLW + sg2 * 8] = v;
    }
}

// ---------------------------------------------------------------------------
// Fused 3-hop poly conv in RANK space, one block per (graph, feature-QUARTER).
// grid = 512 blocks of 512 thr, 34.9 KB LDS. (R5 bank-uniform gather;
// R7 bf16 accout — gemm rounds to bf16 anyway, so producer-side rounding is
// bit-identical and halves the seam traffic.)
// ---------------------------------------------------------------------------
__global__ __launch_bounds__(512, 4) void poly_fused_kernel(
    const float* __restrict__ xin,            // [BN, NF] f32
    unsigned short* __restrict__ accout,      // [BN, NF] bf16, rank space
    const unsigned short* __restrict__ ell,   // [BN][ELLW] rank entries
    const int* __restrict__ ocnt,             // [BN/8] padded oct counts
    const float* __restrict__ dinvr,          // [BN] rank-indexed
    const int* __restrict__ perm,             // [BN] rank -> row
    int permuteIn)
{
    extern __shared__ float lds[];
    unsigned short* w = (unsigned short*)lds;        // (NN+1) rows * QST
    float* dsh = lds + ((NN + 1) * QST * 2) / 4;     // NN floats

    int b = blockIdx.x;
    int g = b & 127;                     // graph (same-graph blocks -> same XCD)
    int q = b >> 7;                      // feature quarter (32 feats)
    int t = threadIdx.x;                 // 0..511
    int wid = t >> 6;                    // 0..7
    int qd  = (t >> 2) & 15;             // quad-in-wave 0..15
    int fbq = t & 3;                     // 16-B chunk 0..3 (8 feats)

    unsigned one_lo = 0x00003F80u;       // bf16x2 (1.0, 0.0)
    unsigned one_hi = 0x3F800000u;       // bf16x2 (0.0, 1.0)

    if (t < NN) dsh[t] = dinvr[(size_t)g * NN + t];
    if (t < QST) w[NN * QST + t] = 0;    // zero sentinel row (bf16 0)

    // 4 passes of 128 ranks; wave handles 16 consecutive ranks (= 2 octs)
    // per pass. Passes 2,3 flip wave order for load balance.
    int rnk[4];
    #pragma unroll
    for (int x = 0; x < 4; ++x) {
        int wl = (x >= 2) ? (7 - wid) : wid;
        rnk[x] = x * 128 + wl * 16 + qd;
    }

    // wave-uniform padded counts: the wave's 16 ranks span octs ob, ob+1
    const int* oc = ocnt + (size_t)g * (NN / 8);
    int co[4];
    #pragma unroll
    for (int x = 0; x < 4; ++x) {
        int ob = (rnk[x] - qd) >> 3;
        co[x] = __builtin_amdgcn_readfirstlane(max(oc[ob], oc[ob + 1]));
    }

    // input row per pass: perm'd for layer 1, identity (coalesced) else
    int px[4];
    if (permuteIn) {
        const int* pmg = perm + (size_t)g * NN;
        #pragma unroll
        for (int x = 0; x < 4; ++x) px[x] = pmg[rnk[x]];
    } else {
        #pragma unroll
        for (int x = 0; x < 4; ++x) px[x] = rnk[x];
    }

    const float* xg = xin + (size_t)g * NN * NF + q * 32 + fbq * 8;

    float acc[4][8];
    #pragma unroll
    for (int x = 0; x < 4; ++x) {
        int row = px[x];
        float4 a0 = *(const float4*)&xg[(size_t)row * NF];
        float4 a1 = *(const float4*)&xg[(size_t)row * NF + 4];
        acc[x][0] = a0.x; acc[x][1] = a0.y; acc[x][2] = a0.z; acc[x][3] = a0.w;
        acc[x][4] = a1.x; acc[x][5] = a1.y; acc[x][6] = a1.z; acc[x][7] = a1.w;
    }

    __syncthreads();                     // dsh + sentinel ready

    #pragma unroll
    for (int x = 0; x < 4; ++x) {
        float di = dsh[rnk[x]];
        unsigned pk[4];
        #pragma unroll
        for (int k = 0; k < 4; ++k) {
            unsigned lo = (unsigned)f2bf(di * acc[x][2 * k]);
            unsigned hi = (unsigned)f2bf(di * acc[x][2 * k + 1]);
            pk[k] = lo | (hi << 16);
        }
        *(uint4*)&w[rnk[x] * QST + fbq * 8] = make_uint4(pk[0], pk[1], pk[2], pk[3]);
    }
    __syncthreads();                     // w init ready

    for (int hop = 0; hop < 3; ++hop) {
        unsigned pst[4][4];              // staged bf16x2 packs per pass
        #pragma unroll
        for (int x = 0; x < 4; ++x) {
            const unsigned short* el =
                ell + ((size_t)g * NN + rnk[x]) * ELLW;
            int cnt = co[x];
            float s[8];
            #pragma unroll
            for (int k = 0; k < 8; ++k) s[k] = 0.0f;

            ushort4 cur = *(const ushort4*)el;     // quad-uniform load
            for (int p = 0; p < cnt; p += 4) {
                ushort4 nxt = cur;
                if (p + 4 < cnt) nxt = *(const ushort4*)(el + p + 4);
                uint4 v0 = *(const uint4*)&w[(int)cur.x * QST + fbq * 8];
                uint4 v1 = *(const uint4*)&w[(int)cur.y * QST + fbq * 8];
                uint4 v2 = *(const uint4*)&w[(int)cur.z * QST + fbq * 8];
                uint4 v3 = *(const uint4*)&w[(int)cur.w * QST + fbq * 8];
                unsigned d[4][4] = {{v0.x, v0.y, v0.z, v0.w},
                                    {v1.x, v1.y, v1.z, v1.w},
                                    {v2.x, v2.y, v2.z, v2.w},
                                    {v3.x, v3.y, v3.z, v3.w}};
                #pragma unroll
                for (int n = 0; n < 4; ++n) {
                    #pragma unroll
                    for (int k = 0; k < 4; ++k) {
                        DOT2LO(s[2 * k],     d[n][k], one_lo);
                        DOT2LO(s[2 * k + 1], d[n][k], one_hi);
                    }
                }
                cur = nxt;
            }

            // fold into acc + pack NOW (dsh is stable): staging = 4 uints
            float di = dsh[rnk[x]];
            #pragma unroll
            for (int k = 0; k < 4; ++k) {
                float zlo = di * s[2 * k];
                float zhi = di * s[2 * k + 1];
                acc[x][2 * k]     += zlo;
                acc[x][2 * k + 1] += zhi;
                unsigned lo = (unsigned)f2bf(di * zlo);
                unsigned hi = (unsigned)f2bf(di * zhi);
                pst[x][k] = lo | (hi << 16);
            }
        }
        __syncthreads();                 // all reads of old w done
        #pragma unroll
        for (int x = 0; x < 4; ++x) {
            *(uint4*)&w[rnk[x] * QST + fbq * 8] =
                make_uint4(pst[x][0], pst[x][1], pst[x][2], pst[x][3]);
        }
        __syncthreads();                 // new w visible
    }

    // coalesced bf16 write at rank positions (16 B per pass per thread)
    unsigned short* og = accout + (size_t)g * NN * NF + q * 32 + fbq * 8;
    #pragma unroll
    for (int x = 0; x < 4; ++x) {
        int rr = rnk[x];
        uint4 pk;
        pk.x = (unsigned)f2bf(acc[x][0]) | ((unsigned)f2bf(acc[x][1]) << 16);
        pk.y = (unsigned)f2bf(acc[x][2]) | ((unsigned)f2bf(acc[x][3]) << 16);
        pk.z = (unsigned)f2bf(acc[x][4]) | ((unsigned)f2bf(acc[x][5]) << 16);
        pk.w = (unsigned)f2bf(acc[x][6]) | ((unsigned)f2bf(acc[x][7]) << 16);
        *(uint4*)&og[(size_t)rr * NF] = pk;
    }
}

// ---------------------------------------------------------------------------
// MFMA bf16 GEMM: Y[65536,128] = relu(bf16X @ bf16(W) + b), optional fused
// deterministic mean-pool partials. (unchanged from R7: bf16 X input,
// fuse=1 skips the dead Y store.)
// ---------------------------------------------------------------------------
__global__ __launch_bounds__(256, 2) void gemm_bias_relu_kernel(
    const unsigned short* __restrict__ X,   // [BN, NF] bf16
    const float* __restrict__ W,
    const float* __restrict__ b, float* __restrict__ Y,
    float* __restrict__ partial, int fuse)
{
    __shared__ __align__(16) unsigned short Wt[NF * WTS];  // [n][k] bf16
    __shared__ float part[4 * NF];

    int t = threadIdx.x;

    // stage Wt = W^T in bf16
    for (int i = t; i < NF * NF / 4; i += 256) {
        int k = i >> 5;                 // W row
        int n4 = (i & 31) * 4;          // W col group
        float4 wv = ((const float4*)W)[i];
        Wt[(n4 + 0) * WTS + k] = f2bf(wv.x);
        Wt[(n4 + 1) * WTS + k] = f2bf(wv.y);
        Wt[(n4 + 2) * WTS + k] = f2bf(wv.z);
        Wt[(n4 + 3) * WTS + k] = f2bf(wv.w);
    }
    __syncthreads();

    int lane = t & 63;
    int wid  = t >> 6;                  // 0..3
    int quad = lane >> 4;               // 0..3
    int l16  = lane & 15;
    int rowA0 = blockIdx.x * 128 + wid * 32;

    // A fragments: direct bf16 16-B loads (no conversion chain)
    union { uint4 q; sh8 v; } af[2][4];
    #pragma unroll
    for (int m = 0; m < 2; ++m) {
        int r = rowA0 + m * 16 + l16;
        const unsigned short* xr = X + (size_t)r * NF + quad * 8;
        #pragma unroll
        for (int kk = 0; kk < 4; ++kk)
            af[m][kk].q = *(const uint4*)(xr + kk * 32);
    }

    f32x4 acc[2][8];
    #pragma unroll
    for (int m = 0; m < 2; ++m)
        #pragma unroll
        for (int c = 0; c < 8; ++c) acc[m][c] = (f32x4){0.f, 0.f, 0.f, 0.f};

    #pragma unroll
    for (int c = 0; c < 8; ++c) {
        const unsigned short* wb = &Wt[(c * 16 + l16) * WTS + quad * 8];
        #pragma unroll
        for (int kk = 0; kk < 4; ++kk) {
            union { uint4 q; sh8 v; } bf_;
            bf_.q = *(const uint4*)(wb + kk * 32);
            acc[0][c] = __builtin_amdgcn_mfma_f32_16x16x32_bf16(
                af[0][kk].v, bf_.v, acc[0][c], 0, 0, 0);
            acc[1][c] = __builtin_amdgcn_mfma_f32_16x16x32_bf16(
                af[1][kk].v, bf_.v, acc[1][c], 0, 0, 0);
        }
    }

    float psum[8];
    #pragma unroll
    for (int c = 0; c < 8; ++c) psum[c] = 0.0f;

    #pragma unroll
    for (int c = 0; c < 8; ++c) {
        int col = c * 16 + l16;
        float bias = b[col];
        #pragma unroll
        for (int m = 0; m < 2; ++m) {
            #pragma unroll
            for (int reg = 0; reg < 4; ++reg) {
                int r = rowA0 + m * 16 + quad * 4 + reg;
                float v = fmaxf(acc[m][c][reg] + bias, 0.0f);
                if (!fuse) Y[(size_t)r * NF + col] = v;
                psum[c] += v;
            }
        }
    }

    if (fuse) {
        // deterministic cross-quad reduction, then cross-wave LDS tree
        #pragma unroll
        for (int c = 0; c < 8; ++c) {
            float v = psum[c];
            v += __shfl_xor(v, 16);
            v += __shfl_xor(v, 32);
            if (lane < 16) part[wid * NF + c * 16 + lane] = v;
        }
        __syncthreads();
        if (t < NF) {
            float s = part[t] + part[NF + t] + part[2 * NF + t]
                    + part[3 * NF + t];
            partial[(size_t)blockIdx.x * NF + t] = s;
        }
    }
}

// ---------------------------------------------------------------------------
// Readout: per graph, mean-pool from gemm2 partials (4 blocks/graph) + MLP.
// ---------------------------------------------------------------------------
__global__ __launch_bounds__(128) void readout_kernel(
    const float* __restrict__ partial,   // [BN/128][NF]
    const float* __restrict__ Wr1, const float* __restrict__ br1,
    const float* __restrict__ Wr2, const float* __restrict__ br2,
    float* __restrict__ out)
{
    __shared__ float hsh[NF];
    __shared__ float r1[64];

    int g = blockIdx.x;
    int t = threadIdx.x;

    const float* pg = partial + (size_t)g * 4 * NF;
    float s = 0.0f;
    #pragma unroll
    for (int j = 0; j < 4; ++j) s += pg[j * NF + t];
    hsh[t] = s * (1.0f / (float)NN);
    __syncthreads();

    if (t < 64) {
        float a = br1[t];
        #pragma unroll 8
        for (int k = 0; k < NF; ++k) a += hsh[k] * Wr1[k * 64 + t];
        r1[t] = fmaxf(a, 0.0f);
    }
    __syncthreads();

    if (t < 64) {
        float v = r1[t] * Wr2[t];
        #pragma unroll
        for (int off = 32; off; off >>= 1) v += __shfl_down(v, off);
        if (t == 0) out[g] = v + br2[0];
    }
}

// ---------------------------------------------------------------------------
extern "C" void kernel_launch(void* const* d_in, const int* in_sizes, int n_in,
                              void* d_out, int out_size, void* d_ws, size_t ws_size,
                              hipStream_t stream)
{
    const float* X    = (const float*)d_in[0];
    // d_in[1] = batch (unused; nodes already grouped per graph)
    const int*   ei   = (const int*)d_in[2];
    const float* W1   = (const float*)d_in[3];
    const float* b1   = (const float*)d_in[4];
    const float* W2   = (const float*)d_in[5];
    const float* b2   = (const float*)d_in[6];
    const float* Wr1  = (const float*)d_in[7];
    const float* br1  = (const float*)d_in[8];
    const float* Wr2  = (const float*)d_in[9];
    const float* br2  = (const float*)d_in[10];
    float* out = (float*)d_out;

    const int* src = ei;
    const int* dst = ei + NE;

    // workspace layout
    char* ws = (char*)d_ws;
    float*          dinvr   = (float*)(ws);                          // 256 KB
    int*            ocnt    = (int*)(ws + (size_t)256 * 1024);       // 32 KB
    int*            perm    = (int*)(ws + (size_t)512 * 1024);       // 256 KB
    float*          partial = (float*)(ws + (size_t)768 * 1024);     // 256 KB
    unsigned short* ell     = (unsigned short*)(ws + (size_t)1024 * 1024); // 8 MB
    unsigned*       bmg     = (unsigned*)(ws + (size_t)9216 * 1024); // 4 MB bitmap
    unsigned short* buf0    = (unsigned short*)(ws + (size_t)16384 * 1024); // 16.7 MB bf16
    float*          buf1    = (float*)(ws + (size_t)49152 * 1024);   // 32 MB f32

    // ---- adjacency build, two stages (R8 split)
    scatter_bitmap_kernel<<<NB * 4, 256, 0, stream>>>(src, dst, bmg);
    rank_ell_kernel<<<NB, 1024, 0, stream>>>(bmg, ell, ocnt, dinvr, perm);

    // bf16 w rows (513 * 64 B) + dsh (512 floats) = 34,880 B
    const size_t LDSSZ = (size_t)(NN + 1) * QST * 2 + NN * 4;

    // ---- Layer 1 (X gathered via perm into rank space; accout bf16)
    poly_fused_kernel<<<NB * 4, 512, LDSSZ, stream>>>(X, buf0, ell, ocnt,
                                                      dinvr, perm, 1);
    gemm_bias_relu_kernel<<<BN / 128, 256, 0, stream>>>(buf0, W1, b1, buf1,
                                                        partial, 0);

    // ---- Layer 2 (all rank space, fully coalesced; accout bf16)
    poly_fused_kernel<<<NB * 4, 512, LDSSZ, stream>>>(buf1, buf0, ell, ocnt,
                                                      dinvr, perm, 0);
    gemm_bias_relu_kernel<<<BN / 128, 256, 0, stream>>>(buf0, W2, b2, buf1,
                                                        partial, 1);

    // ---- Readout from partials
    readout_kernel<<<NB, 128, 0, stream>>>(partial, Wr1, br1, Wr2, br2, out);
}

// Round 9
// 218.207 us; speedup vs baseline: 1.1899x; 1.0096x over previous
//
#include <hip/hip_runtime.h>
#include <hip/hip_bf16.h>

// Problem constants (match reference)
#define NB 128          // graphs
#define NN 512          // nodes per graph
#define NF 128          // input/hidden feature dim
#define BN (NB*NN)      // 65536 total nodes
#define NE (BN*16)      // 1048576 edges
#define EPG 8192        // edges per graph (N*DEG_AVG)
#define WPR 16          // bitmap words per row (512 bits / 32)
#define ELLW 64         // ELL width (max padded degree)
#define QST 32          // poly w row stride in ushorts (64 B: stride==bank-run)
#define SST 72          // ELL staging stride (ushorts)
#define WTS 136         // gemm Wt LDS stride in ushorts (272 B, 16-B aligned)

typedef short sh8 __attribute__((ext_vector_type(8)));
typedef float f32x4 __attribute__((ext_vector_type(4)));

static __device__ __forceinline__ unsigned short f2bf(float f) {
    unsigned u = __float_as_uint(f);
    u += 0x7fffu + ((u >> 16) & 1u);        // round-to-nearest-even
    return (unsigned short)(u >> 16);
}

// acc += bf16_low(pk)  /  acc += bf16_high(pk) via VOP3P dot2 (exact).
#define DOT2LO(acc_, pk_, one_) \
    asm("v_dot2_f32_bf16 %0, %1, %2, %0" : "+v"(acc_) : "v"(pk_), "v"(one_))

// ---------------------------------------------------------------------------
// Build stage A: edge scatter -> per-quarter LDS bitmap -> global.
// 512 blocks (graph, row-quarter) x 256 thr. (unchanged from R8)
// ---------------------------------------------------------------------------
__global__ __launch_bounds__(256) void scatter_bitmap_kernel(
    const int* __restrict__ src, const int* __restrict__ dst,
    unsigned* __restrict__ bmg)               // [NB][NN][WPR]
{
    __shared__ unsigned bm[128 * WPR];        // 8 KB: rows qr*128..qr*128+127
    int b = blockIdx.x;
    int g = b >> 2;
    int qr = b & 3;
    int t = threadIdx.x;                      // 0..255

    for (int i = t; i < 128 * WPR; i += 256) bm[i] = 0u;
    __syncthreads();

    const int4* sg4 = (const int4*)(src + (size_t)g * EPG);
    const int4* dg4 = (const int4*)(dst + (size_t)g * EPG);
    int lo = qr << 7;
    for (int i = t; i < EPG / 4; i += 256) {
        int4 s4 = sg4[i];
        int4 d4 = dg4[i];
        int s, d;
        s = s4.x & (NN - 1); d = d4.x & (NN - 1);
        if ((s >> 7) == qr) atomicOr(&bm[(s - lo) * WPR + (d >> 5)], 1u << (d & 31));
        s = s4.y & (NN - 1); d = d4.y & (NN - 1);
        if ((s >> 7) == qr) atomicOr(&bm[(s - lo) * WPR + (d >> 5)], 1u << (d & 31));
        s = s4.z & (NN - 1); d = d4.z & (NN - 1);
        if ((s >> 7) == qr) atomicOr(&bm[(s - lo) * WPR + (d >> 5)], 1u << (d & 31));
        s = s4.w & (NN - 1); d = d4.w & (NN - 1);
        if ((s >> 7) == qr) atomicOr(&bm[(s - lo) * WPR + (d >> 5)], 1u << (d & 31));
    }
    __syncthreads();

    // coalesced 8 KB dump: 512 uint4 / 256 thr = 2 each
    unsigned* outg = bmg + ((size_t)g * NN + (size_t)qr * 128) * WPR;
    #pragma unroll
    for (int i = t; i < 128 * WPR / 4; i += 256)
        *(uint4*)&outg[i * 4] = *(const uint4*)&bm[i * 4];
}

// ---------------------------------------------------------------------------
// Build stage B (R9): degrees, ranks, ELL extraction + writeout.
// 256 blocks (graph, RANK-HALF) x 1024 thr. vs R8's 128 blocks / 2 thr per
// row: full CU coverage, and extraction is 4 THREADS PER ROW — each quartet
// owns one 4-word bitmap quarter, with exact start offsets from the
// quarter-popc prefix (qp), so concatenation reproduces the original
// sequential entry order bit-identically. Degree+rank are recomputed per
// half-block (cheap, parallel); h==0 writes perm/dinvr/ocnt.
// ---------------------------------------------------------------------------
__global__ __launch_bounds__(1024) void rank_ell_kernel(
    const unsigned* __restrict__ bmg,         // [NB][NN][WPR]
    unsigned short* __restrict__ ell, int* __restrict__ ocnt,
    float* __restrict__ dinvr, int* __restrict__ perm)
{
    __shared__ unsigned short els[256 * SST]; // 36,864 B staging (this half)
    __shared__ int qp[NN * 4];                // per-quarter popc (uncapped)
    __shared__ int cs[NN];                    // capped degree by row
    __shared__ int rdeg[NN];                  // degree by rank
    __shared__ int irank[NN];                 // row -> rank
    __shared__ int prow[NN];                  // rank -> row
    __shared__ int prk[NN];                   // partial rank from scanner A
    int b = blockIdx.x;
    int g = b >> 1;
    int h = b & 1;                            // rank half: [h*256, h*256+256)
    int t = threadIdx.x;                      // 0..1023

    // ---- degree phase: 2 thr/row, each popcounts 2 quarters (4+4 words)
    {
        int r = t & 511, hf = t >> 9;
        const unsigned* bgr = bmg + ((size_t)g * NN + r) * WPR + hf * 8;
        uint4 a = *(const uint4*)bgr;
        uint4 c = *(const uint4*)(bgr + 4);
        qp[r * 4 + hf * 2]     = __popc(a.x) + __popc(a.y) + __popc(a.z) + __popc(a.w);
        qp[r * 4 + hf * 2 + 1] = __popc(c.x) + __popc(c.y) + __popc(c.z) + __popc(c.w);
    }
    __syncthreads();
    if (t < NN) {
        int d = qp[t * 4] + qp[t * 4 + 1] + qp[t * 4 + 2] + qp[t * 4 + 3];
        cs[t] = (d > ELLW) ? ELLW : d;
    }
    __syncthreads();

    // ---- rank phase: ascending (deg, row); 2 thr/row scan half of cs each
    {
        int r = t & 511, hf = t >> 9;
        int deg_r = cs[r];
        const int4* c4 = (const int4*)cs;
        int ib = hf * 64;
        int pcnt = 0;
        #pragma unroll 8
        for (int ii = 0; ii < 64; ++ii) {
            int4 v = c4[ib + ii];
            int i0 = (ib + ii) * 4;
            pcnt += (v.x < deg_r) || (v.x == deg_r && (i0 + 0) < r);
            pcnt += (v.y < deg_r) || (v.y == deg_r && (i0 + 1) < r);
            pcnt += (v.z < deg_r) || (v.z == deg_r && (i0 + 2) < r);
            pcnt += (v.w < deg_r) || (v.w == deg_r && (i0 + 3) < r);
        }
        if (!hf) prk[r] = pcnt;
        __syncthreads();
        if (hf) {
            int rk = prk[r] + pcnt;
            irank[r] = rk;
            rdeg[rk] = deg_r;
            prow[rk] = r;
            if (h == 0) {
                perm[(size_t)g * NN + rk] = r;
                dinvr[(size_t)g * NN + rk] =
                    (deg_r > 0) ? rsqrtf((float)deg_r) : 0.0f;
            }
        }
    }
    __syncthreads();                          // irank/prow/rdeg visible

    if (h == 0 && t < NN / 8) {
        int m = rdeg[t * 8 + 7];              // ascending: oct max = last
        ocnt[(size_t)g * (NN / 8) + t] = (m + 3) & ~3;
    }

    // ---- extraction: 4 thr per rank of this half; quartet member qw owns
    // bitmap words [4qw, 4qw+4). Start offset = prefix of quarter popcs ->
    // concatenated output order == original sequential order.
    {
        int rkl = t >> 2;                     // 0..255
        int qw  = t & 3;                      // quarter index
        int rk  = h * 256 + rkl;
        int row = prow[rk];
        const unsigned* bq = bmg + ((size_t)g * NN + row) * WPR + qw * 4;
        uint4 bv = *(const uint4*)bq;
        unsigned wbits[4] = {bv.x, bv.y, bv.z, bv.w};
        int c = 0;
        #pragma unroll
        for (int j = 0; j < 3; ++j) c += (j < qw) ? qp[row * 4 + j] : 0;
        unsigned short* er = &els[rkl * SST];
        #pragma unroll
        for (int w = 0; w < 4; ++w) {
            unsigned bits = wbits[w];
            while (bits) {
                int j = __ffs(bits) - 1;
                bits &= bits - 1;
                if (c < ELLW) er[c] = (unsigned short)irank[(qw * 4 + w) * 32 + j];
                ++c;
            }
        }
        if (qw == 3) {                        // c now == total (uncapped)
            int cc = (c > ELLW) ? ELLW : c;
            for (int p = cc; p < ELLW; ++p) er[p] = (unsigned short)NN;
        }
    }
    __syncthreads();                          // staging complete

    // ---- writeout: 256 rows x 128 B = 32 KB, 2 uint4 per thread
    unsigned short* outb = ell + ((size_t)g * NN + (size_t)h * 256) * ELLW;
    for (int idx = t; idx < 256 * 8; idx += 1024) {
        int r2 = idx >> 3, sg2 = idx & 7;
        uint4 v = *(const uint4*)&els[r2 * SST + sg2 * 8];
        *(uint4*)&outb[(size_t)r2 * ELLW + sg2 * 8] = v;
    }
}

// ---------------------------------------------------------------------------
// Fused 3-hop poly conv in RANK space, one block per (graph, feature-QUARTER).
// grid = 512 blocks of 512 thr, 34.9 KB LDS. (R5 bank-uniform gather;
// R7 bf16 accout.) Unchanged.
// ---------------------------------------------------------------------------
__global__ __launch_bounds__(512, 4) void poly_fused_kernel(
    const float* __restrict__ xin,            // [BN, NF] f32
    unsigned short* __restrict__ accout,      // [BN, NF] bf16, rank space
    const unsigned short* __restrict__ ell,   // [BN][ELLW] rank entries
    const int* __restrict__ ocnt,             // [BN/8] padded oct counts
    const float* __restrict__ dinvr,          // [BN] rank-indexed
    const int* __restrict__ perm,             // [BN] rank -> row
    int permuteIn)
{
    extern __shared__ float lds[];
    unsigned short* w = (unsigned short*)lds;        // (NN+1) rows * QST
    float* dsh = lds + ((NN + 1) * QST * 2) / 4;     // NN floats

    int b = blockIdx.x;
    int g = b & 127;                     // graph (same-graph blocks -> same XCD)
    int q = b >> 7;                      // feature quarter (32 feats)
    int t = threadIdx.x;                 // 0..511
    int wid = t >> 6;                    // 0..7
    int qd  = (t >> 2) & 15;             // quad-in-wave 0..15
    int fbq = t & 3;                     // 16-B chunk 0..3 (8 feats)

    unsigned one_lo = 0x00003F80u;       // bf16x2 (1.0, 0.0)
    unsigned one_hi = 0x3F800000u;       // bf16x2 (0.0, 1.0)

    if (t < NN) dsh[t] = dinvr[(size_t)g * NN + t];
    if (t < QST) w[NN * QST + t] = 0;    // zero sentinel row (bf16 0)

    // 4 passes of 128 ranks; wave handles 16 consecutive ranks (= 2 octs)
    // per pass. Passes 2,3 flip wave order for load balance.
    int rnk[4];
    #pragma unroll
    for (int x = 0; x < 4; ++x) {
        int wl = (x >= 2) ? (7 - wid) : wid;
        rnk[x] = x * 128 + wl * 16 + qd;
    }

    // wave-uniform padded counts: the wave's 16 ranks span octs ob, ob+1
    const int* oc = ocnt + (size_t)g * (NN / 8);
    int co[4];
    #pragma unroll
    for (int x = 0; x < 4; ++x) {
        int ob = (rnk[x] - qd) >> 3;
        co[x] = __builtin_amdgcn_readfirstlane(max(oc[ob], oc[ob + 1]));
    }

    // input row per pass: perm'd for layer 1, identity (coalesced) else
    int px[4];
    if (permuteIn) {
        const int* pmg = perm + (size_t)g * NN;
        #pragma unroll
        for (int x = 0; x < 4; ++x) px[x] = pmg[rnk[x]];
    } else {
        #pragma unroll
        for (int x = 0; x < 4; ++x) px[x] = rnk[x];
    }

    const float* xg = xin + (size_t)g * NN * NF + q * 32 + fbq * 8;

    float acc[4][8];
    #pragma unroll
    for (int x = 0; x < 4; ++x) {
        int row = px[x];
        float4 a0 = *(const float4*)&xg[(size_t)row * NF];
        float4 a1 = *(const float4*)&xg[(size_t)row * NF + 4];
        acc[x][0] = a0.x; acc[x][1] = a0.y; acc[x][2] = a0.z; acc[x][3] = a0.w;
        acc[x][4] = a1.x; acc[x][5] = a1.y; acc[x][6] = a1.z; acc[x][7] = a1.w;
    }

    __syncthreads();                     // dsh + sentinel ready

    #pragma unroll
    for (int x = 0; x < 4; ++x) {
        float di = dsh[rnk[x]];
        unsigned pk[4];
        #pragma unroll
        for (int k = 0; k < 4; ++k) {
            unsigned lo = (unsigned)f2bf(di * acc[x][2 * k]);
            unsigned hi = (unsigned)f2bf(di * acc[x][2 * k + 1]);
            pk[k] = lo | (hi << 16);
        }
        *(uint4*)&w[rnk[x] * QST + fbq * 8] = make_uint4(pk[0], pk[1], pk[2], pk[3]);
    }
    __syncthreads();                     // w init ready

    for (int hop = 0; hop < 3; ++hop) {
        unsigned pst[4][4];              // staged bf16x2 packs per pass
        #pragma unroll
        for (int x = 0; x < 4; ++x) {
            const unsigned short* el =
                ell + ((size_t)g * NN + rnk[x]) * ELLW;
            int cnt = co[x];
            float s[8];
            #pragma unroll
            for (int k = 0; k < 8; ++k) s[k] = 0.0f;

            ushort4 cur = *(const ushort4*)el;     // quad-uniform load
            for (int p = 0; p < cnt; p += 4) {
                ushort4 nxt = cur;
                if (p + 4 < cnt) nxt = *(const ushort4*)(el + p + 4);
                uint4 v0 = *(const uint4*)&w[(int)cur.x * QST + fbq * 8];
                uint4 v1 = *(const uint4*)&w[(int)cur.y * QST + fbq * 8];
                uint4 v2 = *(const uint4*)&w[(int)cur.z * QST + fbq * 8];
                uint4 v3 = *(const uint4*)&w[(int)cur.w * QST + fbq * 8];
                unsigned d[4][4] = {{v0.x, v0.y, v0.z, v0.w},
                                    {v1.x, v1.y, v1.z, v1.w},
                                    {v2.x, v2.y, v2.z, v2.w},
                                    {v3.x, v3.y, v3.z, v3.w}};
                #pragma unroll
                for (int n = 0; n < 4; ++n) {
                    #pragma unroll
                    for (int k = 0; k < 4; ++k) {
                        DOT2LO(s[2 * k],     d[n][k], one_lo);
                        DOT2LO(s[2 * k + 1], d[n][k], one_hi);
                    }
                }
                cur = nxt;
            }

            // fold into acc + pack NOW (dsh is stable): staging = 4 uints
            float di = dsh[rnk[x]];
            #pragma unroll
            for (int k = 0; k < 4; ++k) {
                float zlo = di * s[2 * k];
                float zhi = di * s[2 * k + 1];
                acc[x][2 * k]     += zlo;
                acc[x][2 * k + 1] += zhi;
                unsigned lo = (unsigned)f2bf(di * zlo);
                unsigned hi = (unsigned)f2bf(di * zhi);
                pst[x][k] = lo | (hi << 16);
            }
        }
        __syncthreads();                 // all reads of old w done
        #pragma unroll
        for (int x = 0; x < 4; ++x) {
            *(uint4*)&w[rnk[x] * QST + fbq * 8] =
                make_uint4(pst[x][0], pst[x][1], pst[x][2], pst[x][3]);
        }
        __syncthreads();                 // new w visible
    }

    // coalesced bf16 write at rank positions (16 B per pass per thread)
    unsigned short* og = accout + (size_t)g * NN * NF + q * 32 + fbq * 8;
    #pragma unroll
    for (int x = 0; x < 4; ++x) {
        int rr = rnk[x];
        uint4 pk;
        pk.x = (unsigned)f2bf(acc[x][0]) | ((unsigned)f2bf(acc[x][1]) << 16);
        pk.y = (unsigned)f2bf(acc[x][2]) | ((unsigned)f2bf(acc[x][3]) << 16);
        pk.z = (unsigned)f2bf(acc[x][4]) | ((unsigned)f2bf(acc[x][5]) << 16);
        pk.w = (unsigned)f2bf(acc[x][6]) | ((unsigned)f2bf(acc[x][7]) << 16);
        *(uint4*)&og[(size_t)rr * NF] = pk;
    }
}

// ---------------------------------------------------------------------------
// MFMA bf16 GEMM: Y[65536,128] = relu(bf16X @ bf16(W) + b), optional fused
// deterministic mean-pool partials. (unchanged: bf16 X input, fuse=1 skips
// the dead Y store.)
// ---------------------------------------------------------------------------
__global__ __launch_bounds__(256, 2) void gemm_bias_relu_kernel(
    const unsigned short* __restrict__ X,   // [BN, NF] bf16
    const float* __restrict__ W,
    const float* __restrict__ b, float* __restrict__ Y,
    float* __restrict__ partial, int fuse)
{
    __shared__ __align__(16) unsigned short Wt[NF * WTS];  // [n][k] bf16
    __shared__ float part[4 * NF];

    int t = threadIdx.x;

    // stage Wt = W^T in bf16
    for (int i = t; i < NF * NF / 4; i += 256) {
        int k = i >> 5;                 // W row
        int n4 = (i & 31) * 4;          // W col group
        float4 wv = ((const float4*)W)[i];
        Wt[(n4 + 0) * WTS + k] = f2bf(wv.x);
        Wt[(n4 + 1) * WTS + k] = f2bf(wv.y);
        Wt[(n4 + 2) * WTS + k] = f2bf(wv.z);
        Wt[(n4 + 3) * WTS + k] = f2bf(wv.w);
    }
    __syncthreads();

    int lane = t & 63;
    int wid  = t >> 6;                  // 0..3
    int quad = lane >> 4;               // 0..3
    int l16  = lane & 15;
    int rowA0 = blockIdx.x * 128 + wid * 32;

    // A fragments: direct bf16 16-B loads (no conversion chain)
    union { uint4 q; sh8 v; } af[2][4];
    #pragma unroll
    for (int m = 0; m < 2; ++m) {
        int r = rowA0 + m * 16 + l16;
        const unsigned short* xr = X + (size_t)r * NF + quad * 8;
        #pragma unroll
        for (int kk = 0; kk < 4; ++kk)
            af[m][kk].q = *(const uint4*)(xr + kk * 32);
    }

    f32x4 acc[2][8];
    #pragma unroll
    for (int m = 0; m < 2; ++m)
        #pragma unroll
        for (int c = 0; c < 8; ++c) acc[m][c] = (f32x4){0.f, 0.f, 0.f, 0.f};

    #pragma unroll
    for (int c = 0; c < 8; ++c) {
        const unsigned short* wb = &Wt[(c * 16 + l16) * WTS + quad * 8];
        #pragma unroll
        for (int kk = 0; kk < 4; ++kk) {
            union { uint4 q; sh8 v; } bf_;
            bf_.q = *(const uint4*)(wb + kk * 32);
            acc[0][c] = __builtin_amdgcn_mfma_f32_16x16x32_bf16(
                af[0][kk].v, bf_.v, acc[0][c], 0, 0, 0);
            acc[1][c] = __builtin_amdgcn_mfma_f32_16x16x32_bf16(
                af[1][kk].v, bf_.v, acc[1][c], 0, 0, 0);
        }
    }

    float psum[8];
    #pragma unroll
    for (int c = 0; c < 8; ++c) psum[c] = 0.0f;

    #pragma unroll
    for (int c = 0; c < 8; ++c) {
        int col = c * 16 + l16;
        float bias = b[col];
        #pragma unroll
        for (int m = 0; m < 2; ++m) {
            #pragma unroll
            for (int reg = 0; reg < 4; ++reg) {
                int r = rowA0 + m * 16 + quad * 4 + reg;
                float v = fmaxf(acc[m][c][reg] + bias, 0.0f);
                if (!fuse) Y[(size_t)r * NF + col] = v;
                psum[c] += v;
            }
        }
    }

    if (fuse) {
        // deterministic cross-quad reduction, then cross-wave LDS tree
        #pragma unroll
        for (int c = 0; c < 8; ++c) {
            float v = psum[c];
            v += __shfl_xor(v, 16);
            v += __shfl_xor(v, 32);
            if (lane < 16) part[wid * NF + c * 16 + lane] = v;
        }
        __syncthreads();
        if (t < NF) {
            float s = part[t] + part[NF + t] + part[2 * NF + t]
                    + part[3 * NF + t];
            partial[(size_t)blockIdx.x * NF + t] = s;
        }
    }
}

// ---------------------------------------------------------------------------
// Readout: per graph, mean-pool from gemm2 partials (4 blocks/graph) + MLP.
// ---------------------------------------------------------------------------
__global__ __launch_bounds__(128) void readout_kernel(
    const float* __restrict__ partial,   // [BN/128][NF]
    const float* __restrict__ Wr1, const float* __restrict__ br1,
    const float* __restrict__ Wr2, const float* __restrict__ br2,
    float* __restrict__ out)
{
    __shared__ float hsh[NF];
    __shared__ float r1[64];

    int g = blockIdx.x;
    int t = threadIdx.x;

    const float* pg = partial + (size_t)g * 4 * NF;
    float s = 0.0f;
    #pragma unroll
    for (int j = 0; j < 4; ++j) s += pg[j * NF + t];
    hsh[t] = s * (1.0f / (float)NN);
    __syncthreads();

    if (t < 64) {
        float a = br1[t];
        #pragma unroll 8
        for (int k = 0; k < NF; ++k) a += hsh[k] * Wr1[k * 64 + t];
        r1[t] = fmaxf(a, 0.0f);
    }
    __syncthreads();

    if (t < 64) {
        float v = r1[t] * Wr2[t];
        #pragma unroll
        for (int off = 32; off; off >>= 1) v += __shfl_down(v, off);
        if (t == 0) out[g] = v + br2[0];
    }
}

// ---------------------------------------------------------------------------
extern "C" void kernel_launch(void* const* d_in, const int* in_sizes, int n_in,
                              void* d_out, int out_size, void* d_ws, size_t ws_size,
                              hipStream_t stream)
{
    const float* X    = (const float*)d_in[0];
    // d_in[1] = batch (unused; nodes already grouped per graph)
    const int*   ei   = (const int*)d_in[2];
    const float* W1   = (const float*)d_in[3];
    const float* b1   = (const float*)d_in[4];
    const float* W2   = (const float*)d_in[5];
    const float* b2   = (const float*)d_in[6];
    const float* Wr1  = (const float*)d_in[7];
    const float* br1  = (const float*)d_in[8];
    const float* Wr2  = (const float*)d_in[9];
    const float* br2  = (const float*)d_in[10];
    float* out = (float*)d_out;

    const int* src = ei;
    const int* dst = ei + NE;

    // workspace layout
    char* ws = (char*)d_ws;
    float*          dinvr   = (float*)(ws);                          // 256 KB
    int*            ocnt    = (int*)(ws + (size_t)256 * 1024);       // 32 KB
    int*            perm    = (int*)(ws + (size_t)512 * 1024);       // 256 KB
    float*          partial = (float*)(ws + (size_t)768 * 1024);     // 256 KB
    unsigned short* ell     = (unsigned short*)(ws + (size_t)1024 * 1024); // 8 MB
    unsigned*       bmg     = (unsigned*)(ws + (size_t)9216 * 1024); // 4 MB bitmap
    unsigned short* buf0    = (unsigned short*)(ws + (size_t)16384 * 1024); // 16.7 MB bf16
    float*          buf1    = (float*)(ws + (size_t)49152 * 1024);   // 32 MB f32

    // ---- adjacency build, two stages
    scatter_bitmap_kernel<<<NB * 4, 256, 0, stream>>>(src, dst, bmg);
    rank_ell_kernel<<<NB * 2, 1024, 0, stream>>>(bmg, ell, ocnt, dinvr, perm);

    // bf16 w rows (513 * 64 B) + dsh (512 floats) = 34,880 B
    const size_t LDSSZ = (size_t)(NN + 1) * QST * 2 + NN * 4;

    // ---- Layer 1 (X gathered via perm into rank space; accout bf16)
    poly_fused_kernel<<<NB * 4, 512, LDSSZ, stream>>>(X, buf0, ell, ocnt,
                                                      dinvr, perm, 1);
    gemm_bias_relu_kernel<<<BN / 128, 256, 0, stream>>>(buf0, W1, b1, buf1,
                                                        partial, 0);

    // ---- Layer 2 (all rank space, fully coalesced; accout bf16)
    poly_fused_kernel<<<NB * 4, 512, LDSSZ, stream>>>(buf1, buf0, ell, ocnt,
                                                      dinvr, perm, 0);
    gemm_bias_relu_kernel<<<BN / 128, 256, 0, stream>>>(buf0, W2, b2, buf1,
                                                        partial, 1);

    // ---- Readout from partials
    readout_kernel<<<NB, 128, 0, stream>>>(partial, Wr1, br1, Wr2, br2, out);
}

// Round 11
// 212.542 us; speedup vs baseline: 1.2216x; 1.0267x over previous
//
#include <hip/hip_runtime.h>
#include <hip/hip_bf16.h>

// Problem constants (match reference)
#define NB 128          // graphs
#define NN 512          // nodes per graph
#define NF 128          // input/hidden feature dim
#define BN (NB*NN)      // 65536 total nodes
#define NE (BN*16)      // 1048576 edges
#define EPG 8192        // edges per graph (N*DEG_AVG)
#define WPR 16          // bitmap words per row (512 bits / 32)
#define ELLW 64         // ELL width (max padded degree)
#define QST 32          // poly w row stride in ushorts (64 B: stride==bank-run)
#define SST 72          // ELL staging stride (ushorts)
#define WTS 136         // gemm Wt LDS stride in ushorts (272 B, 16-B aligned)

typedef short sh8 __attribute__((ext_vector_type(8)));
typedef float f32x4 __attribute__((ext_vector_type(4)));

static __device__ __forceinline__ unsigned short f2bf(float f) {
    unsigned u = __float_as_uint(f);
    u += 0x7fffu + ((u >> 16) & 1u);        // round-to-nearest-even
    return (unsigned short)(u >> 16);
}

// acc += bf16_low(pk)  /  acc += bf16_high(pk) via VOP3P dot2 (exact).
#define DOT2LO(acc_, pk_, one_) \
    asm("v_dot2_f32_bf16 %0, %1, %2, %0" : "+v"(acc_) : "v"(pk_), "v"(one_))

// ---------------------------------------------------------------------------
// R11 fused build (R10 retry, LDS trimmed to the R8-proven 86,016 B by
// aliasing prk into the els staging region — prk is dead before els is
// written, with a barrier between). One kernel, 256 blocks (graph,
// RANK-HALF) x 1024 thr. Each block privately rebuilds the full graph
// bitmap in LDS (atomicOr idempotent -> identical scatters in the two
// half-blocks are deterministic), then degree/rank/extract/writeout run
// entirely from LDS. vs R9 split: no 4 MB bitmap HBM round-trip, one fewer
// launch+ramp, edge fetch redundancy 4x -> 2x. Outputs bit-identical
// (extraction = R9's quartet + quarter-popc-prefix scheme).
// ---------------------------------------------------------------------------
__global__ __launch_bounds__(1024) void build_fused_kernel(
    const int* __restrict__ src, const int* __restrict__ dst,
    unsigned short* __restrict__ ell, int* __restrict__ ocnt,
    float* __restrict__ dinvr, int* __restrict__ perm)
{
    __shared__ unsigned bm[NN * WPR];         // 32 KB full-graph bitmap
    __shared__ unsigned short els[256 * SST]; // 36,864 B staging (this half)
    __shared__ int qp[NN * 4];                // per-quarter popc (uncapped)
    __shared__ int cs[NN];                    // capped degree by row
    __shared__ int rdeg[NN];                  // degree by rank
    __shared__ int irank[NN];                 // row -> rank
    __shared__ int prow[NN];                  // rank -> row
    int* prk = (int*)els;                     // ALIAS: partial ranks (dead
                                              // before els is written; barrier
                                              // separates the two uses)
    int b = blockIdx.x;
    int g = b >> 1;
    int h = b & 1;                            // rank half: [h*256, h*256+256)
    int t = threadIdx.x;                      // 0..1023

    // ---- zero + scatter (all 8192 edges; idempotent across half-blocks)
    for (int i = t; i < NN * WPR; i += 1024) bm[i] = 0u;
    __syncthreads();

    const int4* sg4 = (const int4*)(src + (size_t)g * EPG);
    const int4* dg4 = (const int4*)(dst + (size_t)g * EPG);
    for (int i = t; i < EPG / 4; i += 1024) {
        int4 s4 = sg4[i];
        int4 d4 = dg4[i];
        int s, d;
        s = s4.x & (NN - 1); d = d4.x & (NN - 1);
        atomicOr(&bm[s * WPR + (d >> 5)], 1u << (d & 31));
        s = s4.y & (NN - 1); d = d4.y & (NN - 1);
        atomicOr(&bm[s * WPR + (d >> 5)], 1u << (d & 31));
        s = s4.z & (NN - 1); d = d4.z & (NN - 1);
        atomicOr(&bm[s * WPR + (d >> 5)], 1u << (d & 31));
        s = s4.w & (NN - 1); d = d4.w & (NN - 1);
        atomicOr(&bm[s * WPR + (d >> 5)], 1u << (d & 31));
    }
    __syncthreads();

    // ---- degree phase: 2 thr/row, each popcounts 2 quarters (from LDS)
    {
        int r = t & 511, hf = t >> 9;
        const unsigned* bgr = &bm[r * WPR + hf * 8];
        uint4 a = *(const uint4*)bgr;
        uint4 c = *(const uint4*)(bgr + 4);
        qp[r * 4 + hf * 2]     = __popc(a.x) + __popc(a.y) + __popc(a.z) + __popc(a.w);
        qp[r * 4 + hf * 2 + 1] = __popc(c.x) + __popc(c.y) + __popc(c.z) + __popc(c.w);
    }
    __syncthreads();
    if (t < NN) {
        int d = qp[t * 4] + qp[t * 4 + 1] + qp[t * 4 + 2] + qp[t * 4 + 3];
        cs[t] = (d > ELLW) ? ELLW : d;
    }
    __syncthreads();

    // ---- rank phase: ascending (deg, row); 2 thr/row scan half of cs each
    {
        int r = t & 511, hf = t >> 9;
        int deg_r = cs[r];
        const int4* c4 = (const int4*)cs;
        int ib = hf * 64;
        int pcnt = 0;
        #pragma unroll 8
        for (int ii = 0; ii < 64; ++ii) {
            int4 v = c4[ib + ii];
            int i0 = (ib + ii) * 4;
            pcnt += (v.x < deg_r) || (v.x == deg_r && (i0 + 0) < r);
            pcnt += (v.y < deg_r) || (v.y == deg_r && (i0 + 1) < r);
            pcnt += (v.z < deg_r) || (v.z == deg_r && (i0 + 2) < r);
            pcnt += (v.w < deg_r) || (v.w == deg_r && (i0 + 3) < r);
        }
        if (!hf) prk[r] = pcnt;
        __syncthreads();
        if (hf) {
            int rk = prk[r] + pcnt;
            irank[r] = rk;
            rdeg[rk] = deg_r;
            prow[rk] = r;
            if (h == 0) {
                perm[(size_t)g * NN + rk] = r;
                dinvr[(size_t)g * NN + rk] =
                    (deg_r > 0) ? rsqrtf((float)deg_r) : 0.0f;
            }
        }
    }
    __syncthreads();                          // irank/prow/rdeg visible;
                                              // prk dead from here on

    if (h == 0 && t < NN / 8) {
        int m = rdeg[t * 8 + 7];              // ascending: oct max = last
        ocnt[(size_t)g * (NN / 8) + t] = (m + 3) & ~3;
    }

    // ---- extraction: 4 thr per rank of this half; quartet member qw owns
    // bitmap words [4qw, 4qw+4). Start offset = prefix of quarter popcs ->
    // concatenated output order == original sequential order (bit-identical).
    {
        int rkl = t >> 2;                     // 0..255
        int qw  = t & 3;                      // quarter index
        int rk  = h * 256 + rkl;
        int row = prow[rk];
        uint4 bv = *(const uint4*)&bm[row * WPR + qw * 4];
        unsigned wbits[4] = {bv.x, bv.y, bv.z, bv.w};
        int c = 0;
        #pragma unroll
        for (int j = 0; j < 3; ++j) c += (j < qw) ? qp[row * 4 + j] : 0;
        unsigned short* er = &els[rkl * SST];
        #pragma unroll
        for (int w = 0; w < 4; ++w) {
            unsigned bits = wbits[w];
            while (bits) {
                int j = __ffs(bits) - 1;
                bits &= bits - 1;
                if (c < ELLW) er[c] = (unsigned short)irank[(qw * 4 + w) * 32 + j];
                ++c;
            }
        }
        if (qw == 3) {                        // c now == total (uncapped)
            int cc = (c > ELLW) ? ELLW : c;
            for (int p = cc; p < ELLW; ++p) er[p] = (unsigned short)NN;
        }
    }
    __syncthreads();                          // staging complete

    // ---- writeout: 256 rows x 128 B = 32 KB, 2 uint4 per thread
    unsigned short* outb = ell + ((size_t)g * NN + (size_t)h * 256) * ELLW;
    for (int idx = t; idx < 256 * 8; idx += 1024) {
        int r2 = idx >> 3, sg2 = idx & 7;
        uint4 v = *(const uint4*)&els[r2 * SST + sg2 * 8];
        *(uint4*)&outb[(size_t)r2 * ELLW + sg2 * 8] = v;
    }
}

// ---------------------------------------------------------------------------
// Fused 3-hop poly conv in RANK space, one block per (graph, feature-QUARTER).
// grid = 512 blocks of 512 thr, 34.9 KB LDS. (R5 bank-uniform gather;
// R7 bf16 accout.) Unchanged.
// ---------------------------------------------------------------------------
__global__ __launch_bounds__(512, 4) void poly_fused_kernel(
    const float* __restrict__ xin,            // [BN, NF] f32
    unsigned short* __restrict__ accout,      // [BN, NF] bf16, rank space
    const unsigned short* __restrict__ ell,   // [BN][ELLW] rank entries
    const int* __restrict__ ocnt,             // [BN/8] padded oct counts
    const float* __restrict__ dinvr,          // [BN] rank-indexed
    const int* __restrict__ perm,             // [BN] rank -> row
    int permuteIn)
{
    extern __shared__ float lds[];
    unsigned short* w = (unsigned short*)lds;        // (NN+1) rows * QST
    float* dsh = lds + ((NN + 1) * QST * 2) / 4;     // NN floats

    int b = blockIdx.x;
    int g = b & 127;                     // graph (same-graph blocks -> same XCD)
    int q = b >> 7;                      // feature quarter (32 feats)
    int t = threadIdx.x;                 // 0..511
    int wid = t >> 6;                    // 0..7
    int qd  = (t >> 2) & 15;             // quad-in-wave 0..15
    int fbq = t & 3;                     // 16-B chunk 0..3 (8 feats)

    unsigned one_lo = 0x00003F80u;       // bf16x2 (1.0, 0.0)
    unsigned one_hi = 0x3F800000u;       // bf16x2 (0.0, 1.0)

    if (t < NN) dsh[t] = dinvr[(size_t)g * NN + t];
    if (t < QST) w[NN * QST + t] = 0;    // zero sentinel row (bf16 0)

    // 4 passes of 128 ranks; wave handles 16 consecutive ranks (= 2 octs)
    // per pass. Passes 2,3 flip wave order for load balance.
    int rnk[4];
    #pragma unroll
    for (int x = 0; x < 4; ++x) {
        int wl = (x >= 2) ? (7 - wid) : wid;
        rnk[x] = x * 128 + wl * 16 + qd;
    }

    // wave-uniform padded counts: the wave's 16 ranks span octs ob, ob+1
    const int* oc = ocnt + (size_t)g * (NN / 8);
    int co[4];
    #pragma unroll
    for (int x = 0; x < 4; ++x) {
        int ob = (rnk[x] - qd) >> 3;
        co[x] = __builtin_amdgcn_readfirstlane(max(oc[ob], oc[ob + 1]));
    }

    // input row per pass: perm'd for layer 1, identity (coalesced) else
    int px[4];
    if (permuteIn) {
        const int* pmg = perm + (size_t)g * NN;
        #pragma unroll
        for (int x = 0; x < 4; ++x) px[x] = pmg[rnk[x]];
    } else {
        #pragma unroll
        for (int x = 0; x < 4; ++x) px[x] = rnk[x];
    }

    const float* xg = xin + (size_t)g * NN * NF + q * 32 + fbq * 8;

    float acc[4][8];
    #pragma unroll
    for (int x = 0; x < 4; ++x) {
        int row = px[x];
        float4 a0 = *(const float4*)&xg[(size_t)row * NF];
        float4 a1 = *(const float4*)&xg[(size_t)row * NF + 4];
        acc[x][0] = a0.x; acc[x][1] = a0.y; acc[x][2] = a0.z; acc[x][3] = a0.w;
        acc[x][4] = a1.x; acc[x][5] = a1.y; acc[x][6] = a1.z; acc[x][7] = a1.w;
    }

    __syncthreads();                     // dsh + sentinel ready

    #pragma unroll
    for (int x = 0; x < 4; ++x) {
        float di = dsh[rnk[x]];
        unsigned pk[4];
        #pragma unroll
        for (int k = 0; k < 4; ++k) {
            unsigned lo = (unsigned)f2bf(di * acc[x][2 * k]);
            unsigned hi = (unsigned)f2bf(di * acc[x][2 * k + 1]);
            pk[k] = lo | (hi << 16);
        }
        *(uint4*)&w[rnk[x] * QST + fbq * 8] = make_uint4(pk[0], pk[1], pk[2], pk[3]);
    }
    __syncthreads();                     // w init ready

    for (int hop = 0; hop < 3; ++hop) {
        unsigned pst[4][4];              // staged bf16x2 packs per pass
        #pragma unroll
        for (int x = 0; x < 4; ++x) {
            const unsigned short* el =
                ell + ((size_t)g * NN + rnk[x]) * ELLW;
            int cnt = co[x];
            float s[8];
            #pragma unroll
            for (int k = 0; k < 8; ++k) s[k] = 0.0f;

            ushort4 cur = *(const ushort4*)el;     // quad-uniform load
            for (int p = 0; p < cnt; p += 4) {
                ushort4 nxt = cur;
                if (p + 4 < cnt) nxt = *(const ushort4*)(el + p + 4);
                uint4 v0 = *(const uint4*)&w[(int)cur.x * QST + fbq * 8];
                uint4 v1 = *(const uint4*)&w[(int)cur.y * QST + fbq * 8];
                uint4 v2 = *(const uint4*)&w[(int)cur.z * QST + fbq * 8];
                uint4 v3 = *(const uint4*)&w[(int)cur.w * QST + fbq * 8];
                unsigned d[4][4] = {{v0.x, v0.y, v0.z, v0.w},
                                    {v1.x, v1.y, v1.z, v1.w},
                                    {v2.x, v2.y, v2.z, v2.w},
                                    {v3.x, v3.y, v3.z, v3.w}};
                #pragma unroll
                for (int n = 0; n < 4; ++n) {
                    #pragma unroll
                    for (int k = 0; k < 4; ++k) {
                        DOT2LO(s[2 * k],     d[n][k], one_lo);
                        DOT2LO(s[2 * k + 1], d[n][k], one_hi);
                    }
                }
                cur = nxt;
            }

            // fold into acc + pack NOW (dsh is stable): staging = 4 uints
            float di = dsh[rnk[x]];
            #pragma unroll
            for (int k = 0; k < 4; ++k) {
                float zlo = di * s[2 * k];
                float zhi = di * s[2 * k + 1];
                acc[x][2 * k]     += zlo;
                acc[x][2 * k + 1] += zhi;
                unsigned lo = (unsigned)f2bf(di * zlo);
                unsigned hi = (unsigned)f2bf(di * zhi);
                pst[x][k] = lo | (hi << 16);
            }
        }
        __syncthreads();                 // all reads of old w done
        #pragma unroll
        for (int x = 0; x < 4; ++x) {
            *(uint4*)&w[rnk[x] * QST + fbq * 8] =
                make_uint4(pst[x][0], pst[x][1], pst[x][2], pst[x][3]);
        }
        __syncthreads();                 // new w visible
    }

    // coalesced bf16 write at rank positions (16 B per pass per thread)
    unsigned short* og = accout + (size_t)g * NN * NF + q * 32 + fbq * 8;
    #pragma unroll
    for (int x = 0; x < 4; ++x) {
        int rr = rnk[x];
        uint4 pk;
        pk.x = (unsigned)f2bf(acc[x][0]) | ((unsigned)f2bf(acc[x][1]) << 16);
        pk.y = (unsigned)f2bf(acc[x][2]) | ((unsigned)f2bf(acc[x][3]) << 16);
        pk.z = (unsigned)f2bf(acc[x][4]) | ((unsigned)f2bf(acc[x][5]) << 16);
        pk.w = (unsigned)f2bf(acc[x][6]) | ((unsigned)f2bf(acc[x][7]) << 16);
        *(uint4*)&og[(size_t)rr * NF] = pk;
    }
}

// ---------------------------------------------------------------------------
// MFMA bf16 GEMM: Y[65536,128] = relu(bf16X @ bf16(W) + b), optional fused
// deterministic mean-pool partials. (unchanged: bf16 X input, fuse=1 skips
// the dead Y store.)
// ---------------------------------------------------------------------------
__global__ __launch_bounds__(256, 2) void gemm_bias_relu_kernel(
    const unsigned short* __restrict__ X,   // [BN, NF] bf16
    const float* __restrict__ W,
    const float* __restrict__ b, float* __restrict__ Y,
    float* __restrict__ partial, int fuse)
{
    __shared__ __align__(16) unsigned short Wt[NF * WTS];  // [n][k] bf16
    __shared__ float part[4 * NF];

    int t = threadIdx.x;

    // stage Wt = W^T in bf16
    for (int i = t; i < NF * NF / 4; i += 256) {
        int k = i >> 5;                 // W row
        int n4 = (i & 31) * 4;          // W col group
        float4 wv = ((const float4*)W)[i];
        Wt[(n4 + 0) * WTS + k] = f2bf(wv.x);
        Wt[(n4 + 1) * WTS + k] = f2bf(wv.y);
        Wt[(n4 + 2) * WTS + k] = f2bf(wv.z);
        Wt[(n4 + 3) * WTS + k] = f2bf(wv.w);
    }
    __syncthreads();

    int lane = t & 63;
    int wid  = t >> 6;                  // 0..3
    int quad = lane >> 4;               // 0..3
    int l16  = lane & 15;
    int rowA0 = blockIdx.x * 128 + wid * 32;

    // A fragments: direct bf16 16-B loads (no conversion chain)
    union { uint4 q; sh8 v; } af[2][4];
    #pragma unroll
    for (int m = 0; m < 2; ++m) {
        int r = rowA0 + m * 16 + l16;
        const unsigned short* xr = X + (size_t)r * NF + quad * 8;
        #pragma unroll
        for (int kk = 0; kk < 4; ++kk)
            af[m][kk].q = *(const uint4*)(xr + kk * 32);
    }

    f32x4 acc[2][8];
    #pragma unroll
    for (int m = 0; m < 2; ++m)
        #pragma unroll
        for (int c = 0; c < 8; ++c) acc[m][c] = (f32x4){0.f, 0.f, 0.f, 0.f};

    #pragma unroll
    for (int c = 0; c < 8; ++c) {
        const unsigned short* wb = &Wt[(c * 16 + l16) * WTS + quad * 8];
        #pragma unroll
        for (int kk = 0; kk < 4; ++kk) {
            union { uint4 q; sh8 v; } bf_;
            bf_.q = *(const uint4*)(wb + kk * 32);
            acc[0][c] = __builtin_amdgcn_mfma_f32_16x16x32_bf16(
                af[0][kk].v, bf_.v, acc[0][c], 0, 0, 0);
            acc[1][c] = __builtin_amdgcn_mfma_f32_16x16x32_bf16(
                af[1][kk].v, bf_.v, acc[1][c], 0, 0, 0);
        }
    }

    float psum[8];
    #pragma unroll
    for (int c = 0; c < 8; ++c) psum[c] = 0.0f;

    #pragma unroll
    for (int c = 0; c < 8; ++c) {
        int col = c * 16 + l16;
        float bias = b[col];
        #pragma unroll
        for (int m = 0; m < 2; ++m) {
            #pragma unroll
            for (int reg = 0; reg < 4; ++reg) {
                int r = rowA0 + m * 16 + quad * 4 + reg;
                float v = fmaxf(acc[m][c][reg] + bias, 0.0f);
                if (!fuse) Y[(size_t)r * NF + col] = v;
                psum[c] += v;
            }
        }
    }

    if (fuse) {
        // deterministic cross-quad reduction, then cross-wave LDS tree
        #pragma unroll
        for (int c = 0; c < 8; ++c) {
            float v = psum[c];
            v += __shfl_xor(v, 16);
            v += __shfl_xor(v, 32);
            if (lane < 16) part[wid * NF + c * 16 + lane] = v;
        }
        __syncthreads();
        if (t < NF) {
            float s = part[t] + part[NF + t] + part[2 * NF + t]
                    + part[3 * NF + t];
            partial[(size_t)blockIdx.x * NF + t] = s;
        }
    }
}

// ---------------------------------------------------------------------------
// Readout: per graph, mean-pool from gemm2 partials (4 blocks/graph) + MLP.
// ---------------------------------------------------------------------------
__global__ __launch_bounds__(128) void readout_kernel(
    const float* __restrict__ partial,   // [BN/128][NF]
    const float* __restrict__ Wr1, const float* __restrict__ br1,
    const float* __restrict__ Wr2, const float* __restrict__ br2,
    float* __restrict__ out)
{
    __shared__ float hsh[NF];
    __shared__ float r1[64];

    int g = blockIdx.x;
    int t = threadIdx.x;

    const float* pg = partial + (size_t)g * 4 * NF;
    float s = 0.0f;
    #pragma unroll
    for (int j = 0; j < 4; ++j) s += pg[j * NF + t];
    hsh[t] = s * (1.0f / (float)NN);
    __syncthreads();

    if (t < 64) {
        float a = br1[t];
        #pragma unroll 8
        for (int k = 0; k < NF; ++k) a += hsh[k] * Wr1[k * 64 + t];
        r1[t] = fmaxf(a, 0.0f);
    }
    __syncthreads();

    if (t < 64) {
        float v = r1[t] * Wr2[t];
        #pragma unroll
        for (int off = 32; off; off >>= 1) v += __shfl_down(v, off);
        if (t == 0) out[g] = v + br2[0];
    }
}

// ---------------------------------------------------------------------------
extern "C" void kernel_launch(void* const* d_in, const int* in_sizes, int n_in,
                              void* d_out, int out_size, void* d_ws, size_t ws_size,
                              hipStream_t stream)
{
    const float* X    = (const float*)d_in[0];
    // d_in[1] = batch (unused; nodes already grouped per graph)
    const int*   ei   = (const int*)d_in[2];
    const float* W1   = (const float*)d_in[3];
    const float* b1   = (const float*)d_in[4];
    const float* W2   = (const float*)d_in[5];
    const float* b2   = (const float*)d_in[6];
    const float* Wr1  = (const float*)d_in[7];
    const float* br1  = (const float*)d_in[8];
    const float* Wr2  = (const float*)d_in[9];
    const float* br2  = (const float*)d_in[10];
    float* out = (float*)d_out;

    const int* src = ei;
    const int* dst = ei + NE;

    // workspace layout
    char* ws = (char*)d_ws;
    float*          dinvr   = (float*)(ws);                          // 256 KB
    int*            ocnt    = (int*)(ws + (size_t)256 * 1024);       // 32 KB
    int*            perm    = (int*)(ws + (size_t)512 * 1024);       // 256 KB
    float*          partial = (float*)(ws + (size_t)768 * 1024);     // 256 KB
    unsigned short* ell     = (unsigned short*)(ws + (size_t)1024 * 1024); // 8 MB
    unsigned short* buf0    = (unsigned short*)(ws + (size_t)16384 * 1024); // 16.7 MB bf16
    float*          buf1    = (float*)(ws + (size_t)49152 * 1024);   // 32 MB f32

    // ---- adjacency build: single fused kernel (graph x rank-half)
    build_fused_kernel<<<NB * 2, 1024, 0, stream>>>(src, dst, ell, ocnt,
                                                    dinvr, perm);

    // bf16 w rows (513 * 64 B) + dsh (512 floats) = 34,880 B
    const size_t LDSSZ = (size_t)(NN + 1) * QST * 2 + NN * 4;

    // ---- Layer 1 (X gathered via perm into rank space; accout bf16)
    poly_fused_kernel<<<NB * 4, 512, LDSSZ, stream>>>(X, buf0, ell, ocnt,
                                                      dinvr, perm, 1);
    gemm_bias_relu_kernel<<<BN / 128, 256, 0, stream>>>(buf0, W1, b1, buf1,
                                                        partial, 0);

    // ---- Layer 2 (all rank space, fully coalesced; accout bf16)
    poly_fused_kernel<<<NB * 4, 512, LDSSZ, stream>>>(buf1, buf0, ell, ocnt,
                                                      dinvr, perm, 0);
    gemm_bias_relu_kernel<<<BN / 128, 256, 0, stream>>>(buf0, W2, b2, buf1,
                                                        partial, 1);

    // ---- Readout from partials
    readout_kernel<<<NB, 128, 0, stream>>>(partial, Wr1, br1, Wr2, br2, out);
}